// Round 1
// baseline (794.386 us; speedup 1.0000x reference)
//
#include <hip/hip_runtime.h>
#include <math.h>

#define BB 512
#define NT 8
#define NR 8
#define LDIM 256
#define LP 16
#define LDPC_N 4096
#define M_A 12288
#define COLCAP 128
#define ROWCAP 64
#define SQ2 1.41421356237309515f

// ---------------- build sparse index lists (transposed, fixed capacity) ----------------
__global__ __launch_bounds__(256) void build_sparse(
    const float* __restrict__ A, int* __restrict__ colcnt, int* __restrict__ rowcnt,
    int* __restrict__ csc_t, int* __restrict__ csr_t) {
  const long long total4 = (long long)M_A * LDPC_N / 4;
  long long stride = (long long)gridDim.x * blockDim.x;
  for (long long t = (long long)blockIdx.x * blockDim.x + threadIdx.x; t < total4; t += stride) {
    float4 a = ((const float4*)A)[t];
    long long base = t * 4;
    float av[4] = {a.x, a.y, a.z, a.w};
#pragma unroll
    for (int l = 0; l < 4; l++) {
      if (av[l] != 0.0f) {
        long long lin = base + l;
        int i = (int)(lin >> 12);      // row (M_A)
        int j = (int)(lin & 4095);     // col (LDPC_N)
        int sc = atomicAdd(&colcnt[j], 1);
        if (sc < COLCAP) csc_t[sc * LDPC_N + j] = i;
        int sr = atomicAdd(&rowcnt[i], 1);
        if (sr < ROWCAP) csr_t[sr * M_A + i] = j;
      }
    }
  }
}

// ---------------- K1: u = clamp( (miu*A^T v + 2lw - 2*sqrt2*res - alpha) * w ) ----------------
__global__ __launch_bounds__(256) void k1_update_u(
    const float* __restrict__ z, const float* __restrict__ lam,
    const float* __restrict__ theta, const float* __restrict__ F,
    const float* __restrict__ lambda_W, const float* __restrict__ Lambda_A,
    const float* __restrict__ miu_p, const float* __restrict__ alpha_p,
    const int* __restrict__ colcnt, const int* __restrict__ csc_t,
    float* __restrict__ out_u) {
  __shared__ float v[M_A];
  int b = blockIdx.x;
  int tid = threadIdx.x;
  const float* zb = z + (size_t)b * M_A;
  const float* lb = lam + (size_t)b * M_A;
  for (int i = tid; i < M_A; i += 256) v[i] = theta[i] - zb[i] - lb[i];
  __syncthreads();
  float miu = miu_p[0], alpha = alpha_p[0];
  float lw = lambda_W[b];
  float fb = 4.0f * lw;
  const float* Fb = F + (size_t)b * (2 * NT * LDIM);
  for (int j = tid; j < LDPC_N; j += 256) {
    int cnt = colcnt[j];
    if (cnt > COLCAP) cnt = COLCAP;
    float s = 0.0f;
    for (int k = 0; k < cnt; k++) s += v[csc_t[k * LDPC_N + j]];
    int ld = j >> 4;
    int nt = (j >> 1) & 7;
    int p = j & 1;
    float res = Fb[(p * NT + nt) * LDIM + ld];
    float q = miu * s + 2.0f * lw - 2.0f * SQ2 * res - alpha;
    float w = 1.0f / (miu * Lambda_A[j] + fb - 2.0f * alpha);
    float u = q * w;
    u = fminf(fmaxf(u, 0.0f), 1.0f);
    out_u[(size_t)b * LDPC_N + j] = u;
  }
}

// ---------------- K2: z / lambda1 update ----------------
__global__ __launch_bounds__(256) void k2_update_z(
    const float* __restrict__ u, const float* __restrict__ z_old,
    const float* __restrict__ lam_old, const float* __restrict__ theta,
    const float* __restrict__ relax_p, const float* __restrict__ acc_p,
    const int* __restrict__ rowcnt, const int* __restrict__ csr_t,
    float* __restrict__ out_z, float* __restrict__ out_lam) {
  __shared__ float su[LDPC_N];
  int b = blockIdx.x;
  int tid = threadIdx.x;
  const float* ub = u + (size_t)b * LDPC_N;
  for (int j = tid; j < LDPC_N; j += 256) su[j] = ub[j];
  __syncthreads();
  float relax = relax_p[0], acc = acc_p[0];
  for (int i = tid; i < M_A; i += 256) {
    int cnt = rowcnt[i];
    if (cnt > ROWCAP) cnt = ROWCAP;
    float s = 0.0f;
    for (int k = 0; k < cnt; k++) s += su[csr_t[k * M_A + i]];
    float th = theta[i];
    float zo = z_old[(size_t)b * M_A + i];
    float lo = lam_old[(size_t)b * M_A + i];
    float ztemp = th - relax * s - (1.0f - relax) * (th - zo) - lo;
    float zn = fmaxf(ztemp, 0.0f);
    float ln = zn - ztemp;  // relu(-ztemp)
    out_z[(size_t)b * M_A + i] = zn + acc * (zn - zo);
    out_lam[(size_t)b * M_A + i] = ln + acc * (ln - lo);
  }
}

// ---------------- K3: per-batch MMSE equalizer + F_new ----------------
__global__ __launch_bounds__(256) void k3_mmse(
    const float* __restrict__ u, const float* __restrict__ real_Xp,
    const float* __restrict__ imag_Xp, const float* __restrict__ sigma2_I,
    const float* __restrict__ YYp, const float* __restrict__ Y,
    const float* __restrict__ lambda_W, const float* __restrict__ factor_p,
    const float* __restrict__ acc_new_in,
    float* __restrict__ out_lw, float* __restrict__ out_F, float* __restrict__ out_accnew) {
  __shared__ float XX[16][545];   // padded: 545 % 32 == 1 -> conflict-free column reads
  __shared__ float R[16][16];
  __shared__ float T[16][8];
  __shared__ float Wc[16][16];
  __shared__ float G[16][16];
  int b = blockIdx.x;
  int tid = threadIdx.x;
  const float* ub = u + (size_t)b * LDPC_N;

  // Build XXp = [[rX rXp iX iXp],[-iX -iXp rX rXp]] rows 0..15, cols 0..543
  for (int idx = tid; idx < 8 * 272; idx += 256) {
    int r = idx / 272, c = idx % 272;
    float vr, vi;
    if (c < 256) {
      float u0 = ub[c * 16 + r * 2 + 0];
      float u1 = ub[c * 16 + r * 2 + 1];
      vr = (1.0f - 2.0f * u0) * (1.0f / SQ2);
      vi = (1.0f - 2.0f * u1) * (1.0f / SQ2);
    } else {
      int pc = c - 256;
      vr = real_Xp[(size_t)b * NT * LP + r * LP + pc];
      vi = imag_Xp[(size_t)b * NT * LP + r * LP + pc];
    }
    XX[r][c] = vr;
    XX[r][272 + c] = vi;
    XX[8 + r][c] = -vi;
    XX[8 + r][272 + c] = vr;
  }
  __syncthreads();

  // R = XX * XX^T + sigma2_I
  {
    int i = tid >> 4, j = tid & 15;
    float s = 0.0f;
    for (int k = 0; k < 544; k++) s += XX[i][k] * XX[j][k];
    R[i][j] = s + sigma2_I[(size_t)b * 256 + i * 16 + j];
  }
  // T = XX * YYp^T  (16 x 8)
  if (tid < 128) {
    int i = tid >> 3, m = tid & 7;
    const float* yb = YYp + (size_t)b * NR * 544 + (size_t)m * 544;
    float s = 0.0f;
    for (int k = 0; k < 544; k++) s += XX[i][k] * yb[k];
    T[i][m] = s;
  }
  __syncthreads();

  // Cholesky (lower) of R in-place; R is SPD (XX XX^T + 0.1 I)
  for (int k = 0; k < 16; k++) {
    if (tid == 0) R[k][k] = sqrtf(R[k][k]);
    __syncthreads();
    if (tid > k && tid < 16) R[tid][k] /= R[k][k];
    __syncthreads();
    {
      int i = tid >> 4, j = tid & 15;
      if (i > k && j > k && j <= i) R[i][j] -= R[i][k] * R[j][k];
    }
    __syncthreads();
  }
  // forward solve L y = T
  for (int r = 0; r < 16; r++) {
    if (tid < 8) {
      float s = T[r][tid];
      for (int c = 0; c < r; c++) s -= R[r][c] * T[c][tid];
      T[r][tid] = s / R[r][r];
    }
    __syncthreads();
  }
  // back solve L^T Wt = y
  for (int r = 15; r >= 0; r--) {
    if (tid < 8) {
      float s = T[r][tid];
      for (int c = r + 1; c < 16; c++) s -= R[c][r] * T[c][tid];
      T[r][tid] = s / R[r][r];
    }
    __syncthreads();
  }
  // Wc = [[rW, iW],[-iW, rW]];  W = Wc^T, so WT = Wc
  {
    int i = tid >> 4, j = tid & 15;
    int ii = i & 7, jj = j & 7;
    float val;
    if (i < 8) val = (j < 8) ? T[ii][jj] : T[8 + ii][jj];
    else       val = (j < 8) ? -T[8 + ii][jj] : T[ii][jj];
    Wc[i][j] = val;
  }
  __syncthreads();
  // G = Wc * Wc^T
  {
    int i = tid >> 4, j = tid & 15;
    float s = 0.0f;
#pragma unroll
    for (int c = 0; c < 16; c++) s += Wc[i][c] * Wc[j][c];
    G[i][j] = s;
  }
  __syncthreads();

  float lw_new = factor_p[0] * lambda_W[b];
  // F_new[r][ld] = lw_new*X[r][ld] + sum_c (Wc[r][c]*Y[c][ld] - G[r][c]*X[c][ld])
  {
    int ld = tid;  // 0..255
    float Xv[16], Yv[16];
#pragma unroll
    for (int c = 0; c < 8; c++) {
      Xv[c] = XX[c][ld];
      Xv[8 + c] = XX[c][272 + ld];
    }
    const float* Yb = Y + (size_t)b * 16 * LDIM;
#pragma unroll
    for (int c = 0; c < 16; c++) Yv[c] = Yb[c * LDIM + ld];
    float* Fb = out_F + (size_t)b * 16 * LDIM;
    for (int r = 0; r < 16; r++) {
      float s = lw_new * Xv[r];
#pragma unroll
      for (int c = 0; c < 16; c++) s += Wc[r][c] * Yv[c] - G[r][c] * Xv[c];
      Fb[r * LDIM + ld] = s;
    }
  }
  if (tid == 0) {
    out_lw[b] = lw_new;
    out_accnew[b] = acc_new_in[b];
  }
}

extern "C" void kernel_launch(void* const* d_in, const int* in_sizes, int n_in,
                              void* d_out, int out_size, void* d_ws, size_t ws_size,
                              hipStream_t stream) {
  const float* sigma2_I  = (const float*)d_in[0];
  const float* Y         = (const float*)d_in[1];
  const float* YYp       = (const float*)d_in[2];
  const float* real_Xp   = (const float*)d_in[3];
  const float* imag_Xp   = (const float*)d_in[4];
  const float* lambda_W  = (const float*)d_in[5];
  const float* F         = (const float*)d_in[6];
  // d_in[7] = u input: unused by the reference (overwritten before use)
  const float* z         = (const float*)d_in[8];
  const float* lam       = (const float*)d_in[9];
  const float* acc_new_i = (const float*)d_in[10];
  const float* A         = (const float*)d_in[11];
  const float* theta     = (const float*)d_in[12];
  const float* Lambda_A  = (const float*)d_in[13];
  const float* miu       = (const float*)d_in[14];
  const float* alpha     = (const float*)d_in[15];
  const float* factor    = (const float*)d_in[16];
  const float* relax     = (const float*)d_in[17];
  const float* acc       = (const float*)d_in[18];

  float* out = (float*)d_out;
  float* out_lw     = out;                                   // 512
  float* out_F      = out_lw + BB;                           // 512*16*256
  float* out_u      = out_F + (size_t)BB * 2 * NT * LDIM;    // 512*4096
  float* out_z      = out_u + (size_t)BB * LDPC_N;           // 512*12288
  float* out_lam    = out_z + (size_t)BB * M_A;              // 512*12288
  float* out_accnew = out_lam + (size_t)BB * M_A;            // 512

  int* ws = (int*)d_ws;
  int* colcnt = ws;                            // 4096
  int* rowcnt = colcnt + LDPC_N;               // 12288
  int* csc_t  = rowcnt + M_A;                  // COLCAP*4096
  int* csr_t  = csc_t + COLCAP * LDPC_N;       // ROWCAP*12288

  hipMemsetAsync(colcnt, 0, (LDPC_N + M_A) * sizeof(int), stream);
  build_sparse<<<2048, 256, 0, stream>>>(A, colcnt, rowcnt, csc_t, csr_t);
  k1_update_u<<<BB, 256, 0, stream>>>(z, lam, theta, F, lambda_W, Lambda_A,
                                      miu, alpha, colcnt, csc_t, out_u);
  k2_update_z<<<BB, 256, 0, stream>>>(out_u, z, lam, theta, relax, acc,
                                      rowcnt, csr_t, out_z, out_lam);
  k3_mmse<<<BB, 256, 0, stream>>>(out_u, real_Xp, imag_Xp, sigma2_I, YYp, Y,
                                  lambda_W, factor, acc_new_i,
                                  out_lw, out_F, out_accnew);
}

// Round 2
// 621.018 us; speedup vs baseline: 1.2792x; 1.2792x over previous
//
#include <hip/hip_runtime.h>
#include <math.h>

#define BB 512
#define NT 8
#define NR 8
#define LDIM 256
#define LP 16
#define LDPC_N 4096
#define M_A 12288
#define COLCAP 128
#define ROWCAP 64
#define SQ2 1.41421356237309515f

// ---------------- build sparse index lists (contiguous per col/row) ----------------
__global__ __launch_bounds__(256) void build_sparse(
    const float* __restrict__ A, int* __restrict__ colcnt, int* __restrict__ rowcnt,
    int* __restrict__ csc_c, int* __restrict__ csr_c) {
  const long long total4 = (long long)M_A * LDPC_N / 4;
  long long stride = (long long)gridDim.x * blockDim.x;
  for (long long t = (long long)blockIdx.x * blockDim.x + threadIdx.x; t < total4; t += stride) {
    float4 a = ((const float4*)A)[t];
    long long base = t * 4;
    float av[4] = {a.x, a.y, a.z, a.w};
#pragma unroll
    for (int l = 0; l < 4; l++) {
      if (av[l] != 0.0f) {
        long long lin = base + l;
        int i = (int)(lin >> 12);      // row (M_A)
        int j = (int)(lin & 4095);     // col (LDPC_N)
        int sc = atomicAdd(&colcnt[j], 1);
        if (sc < COLCAP) csc_c[j * COLCAP + sc] = i;
        int sr = atomicAdd(&rowcnt[i], 1);
        if (sr < ROWCAP) csr_c[i * ROWCAP + sr] = j;
      }
    }
  }
}

// ---------------- T1: VT[i][b] = theta[i] - z[b][i] - lam[b][i] (tiled transpose) ----------------
__global__ __launch_bounds__(256) void t1_vt(
    const float* __restrict__ z, const float* __restrict__ lam,
    const float* __restrict__ theta, float* __restrict__ VT) {
  __shared__ float tile[32 * 33];
  int i0 = blockIdx.x * 32, b0 = blockIdx.y * 32;
  {
    int il = threadIdx.x & 31, bq = threadIdx.x >> 5;  // bq 0..7
    float th = theta[i0 + il];
#pragma unroll
    for (int m = 0; m < 4; m++) {
      int bl = bq + m * 8;
      size_t off = (size_t)(b0 + bl) * M_A + i0 + il;
      tile[il * 33 + bl] = th - z[off] - lam[off];
    }
  }
  __syncthreads();
  {
    int bl = threadIdx.x & 31, iq = threadIdx.x >> 5;
#pragma unroll
    for (int m = 0; m < 4; m++) {
      int il = iq + m * 8;
      VT[(size_t)(i0 + il) * BB + b0 + bl] = tile[il * 33 + bl];
    }
  }
}

// ---------------- TF: FT[j][b] = res-reordered F ----------------
__global__ __launch_bounds__(256) void tf_ft(const float* __restrict__ F, float* __restrict__ FT) {
  int stride = gridDim.x * blockDim.x;
  for (int t = blockIdx.x * blockDim.x + threadIdx.x; t < BB * LDPC_N; t += stride) {
    int b = t >> 12;
    int cl = t & 4095;
    int c = cl >> 8, ld = cl & 255;
    int j = ld * 16 + (c & 7) * 2 + (c >> 3);
    FT[(size_t)j * BB + b] = F[t];
  }
}

// ---------------- K1: UT[j][b] = clamp((miu*A^T v + 2lw - 2sq2 res - alpha)*w) ----------------
__global__ __launch_bounds__(256) void k1_spmm(
    const float* __restrict__ VT, const float* __restrict__ FT,
    const int* __restrict__ colcnt, const int* __restrict__ csc_c,
    const float* __restrict__ lambda_W, const float* __restrict__ Lambda_A,
    const float* __restrict__ miu_p, const float* __restrict__ alpha_p,
    float* __restrict__ UT) {
  __shared__ int idx[4 * COLCAP];
  __shared__ int cnts[4];
  __shared__ float lamA[4];
  int j0 = blockIdx.x * 4;
  int b = blockIdx.y * 256 + threadIdx.x;
  for (int t = threadIdx.x; t < 4 * COLCAP; t += 256) idx[t] = csc_c[j0 * COLCAP + t];
  if (threadIdx.x < 4) {
    cnts[threadIdx.x] = min(colcnt[j0 + threadIdx.x], COLCAP);
    lamA[threadIdx.x] = Lambda_A[j0 + threadIdx.x];
  }
  __syncthreads();
  float miu = miu_p[0], alpha = alpha_p[0];
  float lw = lambda_W[b];
  float s[4];
#pragma unroll
  for (int c = 0; c < 4; c++) {
    int cnt = cnts[c];
    const int* ic = &idx[c * COLCAP];
    float acc = 0.0f;
    int k = 0;
    for (; k + 3 < cnt; k += 4) {
      int4 i4 = *(const int4*)&ic[k];
      float a0 = VT[(size_t)i4.x * BB + b];
      float a1 = VT[(size_t)i4.y * BB + b];
      float a2 = VT[(size_t)i4.z * BB + b];
      float a3 = VT[(size_t)i4.w * BB + b];
      acc += (a0 + a1) + (a2 + a3);
    }
    for (; k < cnt; k++) acc += VT[(size_t)ic[k] * BB + b];
    s[c] = acc;
  }
#pragma unroll
  for (int c = 0; c < 4; c++) {
    int j = j0 + c;
    float res = FT[(size_t)j * BB + b];
    float q = miu * s[c] + 2.0f * lw - 2.0f * SQ2 * res - alpha;
    float w = 1.0f / (miu * lamA[c] + 4.0f * lw - 2.0f * alpha);
    float u = q * w;
    u = fminf(fmaxf(u, 0.0f), 1.0f);
    UT[(size_t)j * BB + b] = u;
  }
}

// ---------------- TU: out_u[b][j] = UT[j][b] ----------------
__global__ __launch_bounds__(256) void tu_ut(const float* __restrict__ UT, float* __restrict__ out_u) {
  __shared__ float tile[32 * 33];
  int j0 = blockIdx.x * 32, b0 = blockIdx.y * 32;
  {
    int bl = threadIdx.x & 31, jq = threadIdx.x >> 5;
#pragma unroll
    for (int m = 0; m < 4; m++) {
      int jl = jq + m * 8;
      tile[jl * 33 + bl] = UT[(size_t)(j0 + jl) * BB + b0 + bl];
    }
  }
  __syncthreads();
  {
    int jl = threadIdx.x & 31, bq = threadIdx.x >> 5;
#pragma unroll
    for (int m = 0; m < 4; m++) {
      int bl = bq + m * 8;
      out_u[(size_t)(b0 + bl) * LDPC_N + j0 + jl] = tile[jl * 33 + bl];
    }
  }
}

// ---------------- K2: z / lambda1 update (transposed gathers, direct-layout epilogue) ----------------
__global__ __launch_bounds__(256) void k2_spmm(
    const float* __restrict__ UT, const float* __restrict__ z_old,
    const float* __restrict__ lam_old, const float* __restrict__ theta,
    const float* __restrict__ relax_p, const float* __restrict__ acc_p,
    const int* __restrict__ rowcnt, const int* __restrict__ csr_c,
    float* __restrict__ out_z, float* __restrict__ out_lam) {
  __shared__ int idx[8 * ROWCAP];
  __shared__ int cnts[8];
  __shared__ float ths[8];
  int i0 = blockIdx.x * 8;
  int b = blockIdx.y * 256 + threadIdx.x;
  for (int t = threadIdx.x; t < 8 * ROWCAP; t += 256) idx[t] = csr_c[i0 * ROWCAP + t];
  if (threadIdx.x < 8) {
    cnts[threadIdx.x] = min(rowcnt[i0 + threadIdx.x], ROWCAP);
    ths[threadIdx.x] = theta[i0 + threadIdx.x];
  }
  __syncthreads();
  float relax = relax_p[0], acc = acc_p[0];
  const float4* zp = (const float4*)(z_old + (size_t)b * M_A + i0);
  const float4* lp = (const float4*)(lam_old + (size_t)b * M_A + i0);
  float4 zo4[2] = {zp[0], zp[1]};
  float4 lo4[2] = {lp[0], lp[1]};
  float zo[8] = {zo4[0].x, zo4[0].y, zo4[0].z, zo4[0].w, zo4[1].x, zo4[1].y, zo4[1].z, zo4[1].w};
  float lo[8] = {lo4[0].x, lo4[0].y, lo4[0].z, lo4[0].w, lo4[1].x, lo4[1].y, lo4[1].z, lo4[1].w};
  float oz[8], ol[8];
#pragma unroll
  for (int r = 0; r < 8; r++) {
    int cnt = cnts[r];
    const int* ir = &idx[r * ROWCAP];
    float s = 0.0f;
    int k = 0;
    for (; k + 3 < cnt; k += 4) {
      int4 i4 = *(const int4*)&ir[k];
      float a0 = UT[(size_t)i4.x * BB + b];
      float a1 = UT[(size_t)i4.y * BB + b];
      float a2 = UT[(size_t)i4.z * BB + b];
      float a3 = UT[(size_t)i4.w * BB + b];
      s += (a0 + a1) + (a2 + a3);
    }
    for (; k < cnt; k++) s += UT[(size_t)ir[k] * BB + b];
    float th = ths[r];
    float ztemp = th - relax * s - (1.0f - relax) * (th - zo[r]) - lo[r];
    float zn = fmaxf(ztemp, 0.0f);
    float ln = zn - ztemp;
    oz[r] = zn + acc * (zn - zo[r]);
    ol[r] = ln + acc * (ln - lo[r]);
  }
  float4* ozp = (float4*)(out_z + (size_t)b * M_A + i0);
  float4* olp = (float4*)(out_lam + (size_t)b * M_A + i0);
  ozp[0] = make_float4(oz[0], oz[1], oz[2], oz[3]);
  ozp[1] = make_float4(oz[4], oz[5], oz[6], oz[7]);
  olp[0] = make_float4(ol[0], ol[1], ol[2], ol[3]);
  olp[1] = make_float4(ol[4], ol[5], ol[6], ol[7]);
}

// ---------------- K3: per-batch MMSE equalizer + F_new (unchanged) ----------------
__global__ __launch_bounds__(256) void k3_mmse(
    const float* __restrict__ u, const float* __restrict__ real_Xp,
    const float* __restrict__ imag_Xp, const float* __restrict__ sigma2_I,
    const float* __restrict__ YYp, const float* __restrict__ Y,
    const float* __restrict__ lambda_W, const float* __restrict__ factor_p,
    const float* __restrict__ acc_new_in,
    float* __restrict__ out_lw, float* __restrict__ out_F, float* __restrict__ out_accnew) {
  __shared__ float XX[16][545];
  __shared__ float R[16][16];
  __shared__ float T[16][8];
  __shared__ float Wc[16][16];
  __shared__ float G[16][16];
  int b = blockIdx.x;
  int tid = threadIdx.x;
  const float* ub = u + (size_t)b * LDPC_N;

  for (int idx = tid; idx < 8 * 272; idx += 256) {
    int r = idx / 272, c = idx % 272;
    float vr, vi;
    if (c < 256) {
      float u0 = ub[c * 16 + r * 2 + 0];
      float u1 = ub[c * 16 + r * 2 + 1];
      vr = (1.0f - 2.0f * u0) * (1.0f / SQ2);
      vi = (1.0f - 2.0f * u1) * (1.0f / SQ2);
    } else {
      int pc = c - 256;
      vr = real_Xp[(size_t)b * NT * LP + r * LP + pc];
      vi = imag_Xp[(size_t)b * NT * LP + r * LP + pc];
    }
    XX[r][c] = vr;
    XX[r][272 + c] = vi;
    XX[8 + r][c] = -vi;
    XX[8 + r][272 + c] = vr;
  }
  __syncthreads();

  {
    int i = tid >> 4, j = tid & 15;
    float s = 0.0f;
    for (int k = 0; k < 544; k++) s += XX[i][k] * XX[j][k];
    R[i][j] = s + sigma2_I[(size_t)b * 256 + i * 16 + j];
  }
  if (tid < 128) {
    int i = tid >> 3, m = tid & 7;
    const float* yb = YYp + (size_t)b * NR * 544 + (size_t)m * 544;
    float s = 0.0f;
    for (int k = 0; k < 544; k++) s += XX[i][k] * yb[k];
    T[i][m] = s;
  }
  __syncthreads();

  for (int k = 0; k < 16; k++) {
    if (tid == 0) R[k][k] = sqrtf(R[k][k]);
    __syncthreads();
    if (tid > k && tid < 16) R[tid][k] /= R[k][k];
    __syncthreads();
    {
      int i = tid >> 4, j = tid & 15;
      if (i > k && j > k && j <= i) R[i][j] -= R[i][k] * R[j][k];
    }
    __syncthreads();
  }
  for (int r = 0; r < 16; r++) {
    if (tid < 8) {
      float s = T[r][tid];
      for (int c = 0; c < r; c++) s -= R[r][c] * T[c][tid];
      T[r][tid] = s / R[r][r];
    }
    __syncthreads();
  }
  for (int r = 15; r >= 0; r--) {
    if (tid < 8) {
      float s = T[r][tid];
      for (int c = r + 1; c < 16; c++) s -= R[c][r] * T[c][tid];
      T[r][tid] = s / R[r][r];
    }
    __syncthreads();
  }
  {
    int i = tid >> 4, j = tid & 15;
    int ii = i & 7, jj = j & 7;
    float val;
    if (i < 8) val = (j < 8) ? T[ii][jj] : T[8 + ii][jj];
    else       val = (j < 8) ? -T[8 + ii][jj] : T[ii][jj];
    Wc[i][j] = val;
  }
  __syncthreads();
  {
    int i = tid >> 4, j = tid & 15;
    float s = 0.0f;
#pragma unroll
    for (int c = 0; c < 16; c++) s += Wc[i][c] * Wc[j][c];
    G[i][j] = s;
  }
  __syncthreads();

  float lw_new = factor_p[0] * lambda_W[b];
  {
    int ld = tid;
    float Xv[16], Yv[16];
#pragma unroll
    for (int c = 0; c < 8; c++) {
      Xv[c] = XX[c][ld];
      Xv[8 + c] = XX[c][272 + ld];
    }
    const float* Yb = Y + (size_t)b * 16 * LDIM;
#pragma unroll
    for (int c = 0; c < 16; c++) Yv[c] = Yb[c * LDIM + ld];
    float* Fb = out_F + (size_t)b * 16 * LDIM;
    for (int r = 0; r < 16; r++) {
      float s = lw_new * Xv[r];
#pragma unroll
      for (int c = 0; c < 16; c++) s += Wc[r][c] * Yv[c] - G[r][c] * Xv[c];
      Fb[r * LDIM + ld] = s;
    }
  }
  if (tid == 0) {
    out_lw[b] = lw_new;
    out_accnew[b] = acc_new_in[b];
  }
}

extern "C" void kernel_launch(void* const* d_in, const int* in_sizes, int n_in,
                              void* d_out, int out_size, void* d_ws, size_t ws_size,
                              hipStream_t stream) {
  const float* sigma2_I  = (const float*)d_in[0];
  const float* Y         = (const float*)d_in[1];
  const float* YYp       = (const float*)d_in[2];
  const float* real_Xp   = (const float*)d_in[3];
  const float* imag_Xp   = (const float*)d_in[4];
  const float* lambda_W  = (const float*)d_in[5];
  const float* F         = (const float*)d_in[6];
  const float* z         = (const float*)d_in[8];
  const float* lam       = (const float*)d_in[9];
  const float* acc_new_i = (const float*)d_in[10];
  const float* A         = (const float*)d_in[11];
  const float* theta     = (const float*)d_in[12];
  const float* Lambda_A  = (const float*)d_in[13];
  const float* miu       = (const float*)d_in[14];
  const float* alpha     = (const float*)d_in[15];
  const float* factor    = (const float*)d_in[16];
  const float* relax     = (const float*)d_in[17];
  const float* acc       = (const float*)d_in[18];

  float* out = (float*)d_out;
  float* out_lw     = out;                                   // 512
  float* out_F      = out_lw + BB;                           // 512*16*256  (8.4 MB)
  float* out_u      = out_F + (size_t)BB * 2 * NT * LDIM;    // 512*4096
  float* out_z      = out_u + (size_t)BB * LDPC_N;           // 512*12288  (25.2 MB)
  float* out_lam    = out_z + (size_t)BB * M_A;              // 512*12288  (25.2 MB)
  float* out_accnew = out_lam + (size_t)BB * M_A;            // 512

  // Scratch aliased into not-yet-final d_out regions (stream order makes this safe):
  //  VT (M_A x B, 25.2MB)  -> out_z region   (K2 overwrites after K1 consumed VT)
  //  FT (N x B, 8.4MB)     -> out_lam region (K2 overwrites after K1 consumed FT)
  //  UT (N x B, 8.4MB)     -> out_F region   (K3 overwrites after TU/K2 consumed UT)
  float* VT = out_z;
  float* FT = out_lam;
  float* UT = out_F;

  int* ws = (int*)d_ws;
  int* colcnt = ws;                            // 4096
  int* rowcnt = colcnt + LDPC_N;               // 12288
  int* csc_c  = rowcnt + M_A;                  // COLCAP*4096  (2 MB)
  int* csr_c  = csc_c + COLCAP * LDPC_N;       // ROWCAP*12288 (3 MB)

  hipMemsetAsync(colcnt, 0, (LDPC_N + M_A) * sizeof(int), stream);
  build_sparse<<<2048, 256, 0, stream>>>(A, colcnt, rowcnt, csc_c, csr_c);
  t1_vt<<<dim3(M_A / 32, BB / 32), 256, 0, stream>>>(z, lam, theta, VT);
  tf_ft<<<2048, 256, 0, stream>>>(F, FT);
  k1_spmm<<<dim3(LDPC_N / 4, 2), 256, 0, stream>>>(VT, FT, colcnt, csc_c, lambda_W,
                                                   Lambda_A, miu, alpha, UT);
  tu_ut<<<dim3(LDPC_N / 32, BB / 32), 256, 0, stream>>>(UT, out_u);
  k2_spmm<<<dim3(M_A / 8, 2), 256, 0, stream>>>(UT, z, lam, theta, relax, acc,
                                                rowcnt, csr_c, out_z, out_lam);
  k3_mmse<<<BB, 256, 0, stream>>>(out_u, real_Xp, imag_Xp, sigma2_I, YYp, Y,
                                  lambda_W, factor, acc_new_i,
                                  out_lw, out_F, out_accnew);
}

// Round 3
// 583.055 us; speedup vs baseline: 1.3625x; 1.0651x over previous
//
#include <hip/hip_runtime.h>
#include <math.h>

#define BB 512
#define NT 8
#define NR 8
#define LDIM 256
#define LP 16
#define LDPC_N 4096
#define M_A 12288
#define COLCAP 128
#define ROWCAP 64
#define K2I 16
#define SQ2 1.41421356237309515f
#define INVSQ2 0.70710678118654752f

// ---------------- build sparse index lists (contiguous per col/row) ----------------
__global__ __launch_bounds__(256) void build_sparse(
    const float* __restrict__ A, int* __restrict__ colcnt, int* __restrict__ rowcnt,
    int* __restrict__ csc_c, int* __restrict__ csr_c) {
  const long long total4 = (long long)M_A * LDPC_N / 4;
  long long stride = (long long)gridDim.x * blockDim.x;
  for (long long t = (long long)blockIdx.x * blockDim.x + threadIdx.x; t < total4; t += stride) {
    float4 a = ((const float4*)A)[t];
    long long base = t * 4;
    float av[4] = {a.x, a.y, a.z, a.w};
#pragma unroll
    for (int l = 0; l < 4; l++) {
      if (av[l] != 0.0f) {
        long long lin = base + l;
        int i = (int)(lin >> 12);
        int j = (int)(lin & 4095);
        int sc = atomicAdd(&colcnt[j], 1);
        if (sc < COLCAP) csc_c[j * COLCAP + sc] = i;
        int sr = atomicAdd(&rowcnt[i], 1);
        if (sr < ROWCAP) csr_c[i * ROWCAP + sr] = j;
      }
    }
  }
}

// ---------------- T1: VT[i][b] = theta[i] - z[b][i] - lam[b][i] ----------------
__global__ __launch_bounds__(256) void t1_vt(
    const float* __restrict__ z, const float* __restrict__ lam,
    const float* __restrict__ theta, float* __restrict__ VT) {
  __shared__ float tile[32 * 33];
  int i0 = blockIdx.x * 32, b0 = blockIdx.y * 32;
  {
    int il = threadIdx.x & 31, bq = threadIdx.x >> 5;
    float th = theta[i0 + il];
#pragma unroll
    for (int m = 0; m < 4; m++) {
      int bl = bq + m * 8;
      size_t off = (size_t)(b0 + bl) * M_A + i0 + il;
      tile[il * 33 + bl] = th - z[off] - lam[off];
    }
  }
  __syncthreads();
  {
    int bl = threadIdx.x & 31, iq = threadIdx.x >> 5;
#pragma unroll
    for (int m = 0; m < 4; m++) {
      int il = iq + m * 8;
      VT[(size_t)(i0 + il) * BB + b0 + bl] = tile[il * 33 + bl];
    }
  }
}

// ---------------- TF: FT[j][b], j = ld*16 + nt*2 + p, from F[b][p*8+nt][ld] ----------------
__global__ __launch_bounds__(256) void tf_ft(const float* __restrict__ F, float* __restrict__ FT) {
  __shared__ float tile[256 * 33];  // [j_local][b_local pad33]
  int j0 = blockIdx.x * 256;        // 256 consecutive j = 16 ld x 16 c
  int b0 = blockIdx.y * 32;
  int ld0 = j0 >> 4;
  int cc = threadIdx.x >> 4, dd = threadIdx.x & 15;
  int jl = dd * 16 + ((cc & 7) << 1) + (cc >> 3);
  for (int m = 0; m < 32; m++) {
    tile[jl * 33 + m] = F[(size_t)(b0 + m) * 4096 + cc * 256 + ld0 + dd];
  }
  __syncthreads();
  int bl = threadIdx.x & 31, jq = threadIdx.x >> 5;
  for (int jj = 0; jj < 32; jj++) {
    int jlo = jq * 32 + jj;
    FT[(size_t)(j0 + jlo) * BB + b0 + bl] = tile[jlo * 33 + bl];
  }
}

// ---------------- K1: UT[j][b], all 512 b per block ----------------
__global__ __launch_bounds__(512) void k1_spmm(
    const float* __restrict__ VT, const float* __restrict__ FT,
    const int* __restrict__ colcnt, const int* __restrict__ csc_c,
    const float* __restrict__ lambda_W, const float* __restrict__ Lambda_A,
    const float* __restrict__ miu_p, const float* __restrict__ alpha_p,
    float* __restrict__ UT) {
  __shared__ int idx[8 * COLCAP];
  __shared__ int cnts[8];
  __shared__ float lamA[8];
  int j0 = blockIdx.x * 8;
  int b = threadIdx.x;
  for (int t = threadIdx.x; t < 8 * COLCAP; t += 512) idx[t] = csc_c[j0 * COLCAP + t];
  if (threadIdx.x < 8) {
    cnts[threadIdx.x] = min(colcnt[j0 + threadIdx.x], COLCAP);
    lamA[threadIdx.x] = Lambda_A[j0 + threadIdx.x];
  }
  __syncthreads();
  float miu = miu_p[0], alpha = alpha_p[0];
  float lw = lambda_W[b];
#pragma unroll
  for (int c = 0; c < 8; c++) {
    int cnt = cnts[c];
    const int* ic = &idx[c * COLCAP];
    float acc = 0.0f;
    int k = 0;
    for (; k + 3 < cnt; k += 4) {
      int4 i4 = *(const int4*)&ic[k];
      float a0 = VT[(size_t)i4.x * BB + b];
      float a1 = VT[(size_t)i4.y * BB + b];
      float a2 = VT[(size_t)i4.z * BB + b];
      float a3 = VT[(size_t)i4.w * BB + b];
      acc += (a0 + a1) + (a2 + a3);
    }
    for (; k < cnt; k++) acc += VT[(size_t)ic[k] * BB + b];
    int j = j0 + c;
    float res = FT[(size_t)j * BB + b];
    float q = miu * acc + 2.0f * lw - 2.0f * SQ2 * res - alpha;
    float w = 1.0f / (miu * lamA[c] + 4.0f * lw - 2.0f * alpha);
    float u = q * w;
    u = fminf(fmaxf(u, 0.0f), 1.0f);
    UT[(size_t)j * BB + b] = u;
  }
}

// ---------------- TU: out_u[b][j] = UT[j][b] ----------------
__global__ __launch_bounds__(256) void tu_ut(const float* __restrict__ UT, float* __restrict__ out_u) {
  __shared__ float tile[32 * 33];
  int j0 = blockIdx.x * 32, b0 = blockIdx.y * 32;
  {
    int bl = threadIdx.x & 31, jq = threadIdx.x >> 5;
#pragma unroll
    for (int m = 0; m < 4; m++) {
      int jl = jq + m * 8;
      tile[jl * 33 + bl] = UT[(size_t)(j0 + jl) * BB + b0 + bl];
    }
  }
  __syncthreads();
  {
    int jl = threadIdx.x & 31, bq = threadIdx.x >> 5;
#pragma unroll
    for (int m = 0; m < 4; m++) {
      int bl = bq + m * 8;
      out_u[(size_t)(b0 + bl) * LDPC_N + j0 + jl] = tile[jl * 33 + bl];
    }
  }
}

// ---------------- K2: i-tile 16, all-b gathers, lane-remapped coalesced epilogue ----------------
__global__ __launch_bounds__(512) void k2_spmm(
    const float* __restrict__ UT, const float* __restrict__ z_old,
    const float* __restrict__ lam_old, const float* __restrict__ theta,
    const float* __restrict__ relax_p, const float* __restrict__ acc_p,
    const int* __restrict__ rowcnt, const int* __restrict__ csr_c,
    float* __restrict__ out_z, float* __restrict__ out_lam) {
  __shared__ int idx[K2I * ROWCAP];
  __shared__ int cnts[K2I];
  __shared__ float ths[K2I];
  __shared__ float ssum[K2I * 513];
  int i0 = blockIdx.x * K2I;
  int tid = threadIdx.x;
  for (int t = tid; t < K2I * ROWCAP; t += 512) idx[t] = csr_c[i0 * ROWCAP + t];
  if (tid < K2I) {
    cnts[tid] = min(rowcnt[i0 + tid], ROWCAP);
    ths[tid] = theta[i0 + tid];
  }
  __syncthreads();
  {
    int b = tid;
    for (int r = 0; r < K2I; r++) {
      int cnt = cnts[r];
      const int* ir = &idx[r * ROWCAP];
      float s = 0.0f;
      int k = 0;
      for (; k + 3 < cnt; k += 4) {
        int4 i4 = *(const int4*)&ir[k];
        float a0 = UT[(size_t)i4.x * BB + b];
        float a1 = UT[(size_t)i4.y * BB + b];
        float a2 = UT[(size_t)i4.z * BB + b];
        float a3 = UT[(size_t)i4.w * BB + b];
        s += (a0 + a1) + (a2 + a3);
      }
      for (; k < cnt; k++) s += UT[(size_t)ir[k] * BB + b];
      ssum[r * 513 + b] = s;
    }
  }
  __syncthreads();
  float relax = relax_p[0], acc = acc_p[0];
  int iw = tid & 15, bq = tid >> 4;  // bq 0..31
  float th = ths[iw];
  for (int p = 0; p < 16; p++) {
    int b = p * 32 + bq;
    size_t off = (size_t)b * M_A + i0 + iw;
    float zo = z_old[off];
    float lo = lam_old[off];
    float s = ssum[iw * 513 + b];
    float ztemp = th - relax * s - (1.0f - relax) * (th - zo) - lo;
    float zn = fmaxf(ztemp, 0.0f);
    float ln = zn - ztemp;
    out_z[off] = zn + acc * (zn - zo);
    out_lam[off] = ln + acc * (ln - lo);
  }
}

// ---------------- K3a: per-batch solve -> Wc, G (one wave per batch) ----------------
#define RL(i, j) Rs[(i) * 17 + (j)]
__global__ __launch_bounds__(64) void k3a_solve(
    const float* __restrict__ u, const float* __restrict__ real_Xp,
    const float* __restrict__ imag_Xp, const float* __restrict__ sigma2_I,
    const float* __restrict__ YYp, const float* __restrict__ lambda_W,
    const float* __restrict__ factor_p, const float* __restrict__ acc_new_in,
    float* __restrict__ WcG, float* __restrict__ out_lw, float* __restrict__ out_accnew) {
  __shared__ float XX[16][545];
  __shared__ float yy[8 * 545];
  __shared__ float Rs[16 * 17];
  __shared__ float invd[16];
  __shared__ float Tm[16][8];
  __shared__ float Wc[16][16];
  int b = blockIdx.x;
  int tid = threadIdx.x;

  // build XX from u: float4 = rows (2k,2k+1) x (re,im) at col ld
  const float4* u4 = (const float4*)(u + (size_t)b * LDPC_N);
  for (int m = tid; m < 1024; m += 64) {
    float4 q = u4[m];
    int ld = m >> 2;
    int nt = (2 * m) & 7;  // even
    float vr0 = (1.0f - 2.0f * q.x) * INVSQ2;
    float vi0 = (1.0f - 2.0f * q.y) * INVSQ2;
    float vr1 = (1.0f - 2.0f * q.z) * INVSQ2;
    float vi1 = (1.0f - 2.0f * q.w) * INVSQ2;
    XX[nt][ld] = vr0;     XX[nt][272 + ld] = vi0;
    XX[8 + nt][ld] = -vi0; XX[8 + nt][272 + ld] = vr0;
    XX[nt + 1][ld] = vr1;     XX[nt + 1][272 + ld] = vi1;
    XX[9 + nt][ld] = -vi1;    XX[9 + nt][272 + ld] = vr1;
  }
  for (int t = tid; t < 128; t += 64) {
    int r = t >> 4, pc = t & 15;
    float vr = real_Xp[(size_t)b * 128 + t];
    float vi = imag_Xp[(size_t)b * 128 + t];
    XX[r][256 + pc] = vr;      XX[r][528 + pc] = vi;
    XX[8 + r][256 + pc] = -vi; XX[8 + r][528 + pc] = vr;
  }
  // stage YYp[b] (8 x 544) into padded LDS
  {
    const float4* y4 = (const float4*)(YYp + (size_t)b * NR * 544);
    for (int t = tid; t < 1088; t += 64) {
      float4 v = y4[t];
      int lin = t * 4;
      int row = lin / 544, col = lin % 544;
      float* d = &yy[row * 545 + col];
      d[0] = v.x; d[1] = v.y; d[2] = v.z; d[3] = v.w;
    }
  }
  __syncthreads();

  // R lower triangle (136 dots) + sigma
  for (int p = tid; p < 136; p += 64) {
    int i = 0;
    while ((i + 1) * (i + 2) / 2 <= p) i++;
    int j = p - i * (i + 1) / 2;
    float s = 0.0f;
    for (int k = 0; k < 544; k++) s += XX[i][k] * XX[j][k];
    RL(i, j) = s + sigma2_I[(size_t)b * 256 + i * 16 + j];
  }
  // T = XX * YYp^T (16 x 8)
  for (int t = tid; t < 128; t += 64) {
    int i = t >> 3, m = t & 7;
    float s = 0.0f;
    for (int k = 0; k < 544; k++) s += XX[i][k] * yy[m * 545 + k];
    Tm[i][m] = s;
  }
  __syncthreads();

  // Cholesky (right-looking) on lower R
  for (int k = 0; k < 16; k++) {
    if (tid == 0) RL(k, k) = sqrtf(fmaxf(RL(k, k), 1e-30f));
    __syncthreads();
    float dinv = 1.0f / RL(k, k);
    if (tid > k && tid < 16) RL(tid, k) *= dinv;
    if (tid == k) invd[k] = dinv;
    __syncthreads();
    for (int c = tid; c < 256; c += 64) {
      int i = c >> 4, j = c & 15;
      if (i > k && j > k && j <= i) RL(i, j) -= RL(i, k) * RL(j, k);
    }
    __syncthreads();
  }

  // triangular solves: each of 8 lanes owns one RHS column, fully in registers
  if (tid < 8) {
    int m = tid;
    float yv[16], wv[16];
#pragma unroll
    for (int r = 0; r < 16; r++) {
      float s = Tm[r][m];
      for (int c = 0; c < r; c++) s -= RL(r, c) * yv[c];
      yv[r] = s * invd[r];
    }
#pragma unroll
    for (int r = 15; r >= 0; r--) {
      float s = yv[r];
      for (int c = r + 1; c < 16; c++) s -= RL(c, r) * wv[c];
      wv[r] = s * invd[r];
    }
#pragma unroll
    for (int r = 0; r < 16; r++) Tm[r][m] = wv[r];
  }
  __syncthreads();

  // Wc = WT = [[rW, iW],[-iW, rW]]
  for (int c = tid; c < 256; c += 64) {
    int i = c >> 4, j = c & 15;
    int ii = i & 7, jj = j & 7;
    float val;
    if (i < 8) val = (j < 8) ? Tm[ii][jj] : Tm[8 + ii][jj];
    else       val = (j < 8) ? -Tm[8 + ii][jj] : Tm[ii][jj];
    Wc[i][j] = val;
  }
  __syncthreads();
  // emit Wc and G = Wc * Wc^T
  float* og = WcG + (size_t)b * 512;
  for (int c = tid; c < 256; c += 64) {
    int i = c >> 4, j = c & 15;
    float s = 0.0f;
#pragma unroll
    for (int k = 0; k < 16; k++) s += Wc[i][k] * Wc[j][k];
    og[c] = Wc[i][j];
    og[256 + c] = s;
  }
  if (tid == 0) {
    out_lw[b] = factor_p[0] * lambda_W[b];
    out_accnew[b] = acc_new_in[b];
  }
}

// ---------------- K3b: F_new epilogue (coalesced, parallel) ----------------
__global__ __launch_bounds__(256) void k3b_fnew(
    const float* __restrict__ u, const float* __restrict__ Y,
    const float* __restrict__ WcG, const float* __restrict__ lambda_W,
    const float* __restrict__ factor_p, float* __restrict__ out_F) {
  __shared__ float W_s[256];
  __shared__ float G_s[256];
  int b = blockIdx.x;
  int tid = threadIdx.x;
  W_s[tid] = WcG[(size_t)b * 512 + tid];
  G_s[tid] = WcG[(size_t)b * 512 + 256 + tid];
  __syncthreads();
  float lw_new = factor_p[0] * lambda_W[b];
  int ld = tid;
  float Xv[16];
  {
    const float4* u4 = (const float4*)(u + (size_t)b * LDPC_N + ld * 16);
#pragma unroll
    for (int k = 0; k < 4; k++) {
      float4 q = u4[k];
      Xv[2 * k]     = (1.0f - 2.0f * q.x) * INVSQ2;
      Xv[8 + 2 * k] = (1.0f - 2.0f * q.y) * INVSQ2;
      Xv[2 * k + 1]     = (1.0f - 2.0f * q.z) * INVSQ2;
      Xv[9 + 2 * k]     = (1.0f - 2.0f * q.w) * INVSQ2;
    }
  }
  float Yv[16];
  const float* Yb = Y + (size_t)b * 16 * LDIM;
#pragma unroll
  for (int c = 0; c < 16; c++) Yv[c] = Yb[c * LDIM + ld];
  float* Fb = out_F + (size_t)b * 16 * LDIM;
  for (int r = 0; r < 16; r++) {
    float s = lw_new * Xv[r];
#pragma unroll
    for (int c = 0; c < 16; c++) s += W_s[r * 16 + c] * Yv[c] - G_s[r * 16 + c] * Xv[c];
    Fb[r * LDIM + ld] = s;
  }
}

extern "C" void kernel_launch(void* const* d_in, const int* in_sizes, int n_in,
                              void* d_out, int out_size, void* d_ws, size_t ws_size,
                              hipStream_t stream) {
  const float* sigma2_I  = (const float*)d_in[0];
  const float* Y         = (const float*)d_in[1];
  const float* YYp       = (const float*)d_in[2];
  const float* real_Xp   = (const float*)d_in[3];
  const float* imag_Xp   = (const float*)d_in[4];
  const float* lambda_W  = (const float*)d_in[5];
  const float* F         = (const float*)d_in[6];
  const float* z         = (const float*)d_in[8];
  const float* lam       = (const float*)d_in[9];
  const float* acc_new_i = (const float*)d_in[10];
  const float* A         = (const float*)d_in[11];
  const float* theta     = (const float*)d_in[12];
  const float* Lambda_A  = (const float*)d_in[13];
  const float* miu       = (const float*)d_in[14];
  const float* alpha     = (const float*)d_in[15];
  const float* factor    = (const float*)d_in[16];
  const float* relax     = (const float*)d_in[17];
  const float* acc       = (const float*)d_in[18];

  float* out = (float*)d_out;
  float* out_lw     = out;
  float* out_F      = out_lw + BB;
  float* out_u      = out_F + (size_t)BB * 2 * NT * LDIM;
  float* out_z      = out_u + (size_t)BB * LDPC_N;
  float* out_lam    = out_z + (size_t)BB * M_A;
  float* out_accnew = out_lam + (size_t)BB * M_A;

  // Scratch aliased into not-yet-final d_out regions (stream order makes this safe):
  float* VT = out_z;    // consumed by k1, overwritten by k2
  float* FT = out_lam;  // consumed by k1, overwritten by k2
  float* UT = out_F;    // consumed by k2/tu, overwritten by k3b

  int* ws = (int*)d_ws;
  int* colcnt = ws;                            // 4096
  int* rowcnt = colcnt + LDPC_N;               // 12288
  int* csc_c  = rowcnt + M_A;                  // COLCAP*4096
  int* csr_c  = csc_c + COLCAP * LDPC_N;       // ROWCAP*12288
  float* WcG  = (float*)(csr_c + ROWCAP * M_A);  // 512*512 floats

  hipMemsetAsync(colcnt, 0, (LDPC_N + M_A) * sizeof(int), stream);
  build_sparse<<<2048, 256, 0, stream>>>(A, colcnt, rowcnt, csc_c, csr_c);
  t1_vt<<<dim3(M_A / 32, BB / 32), 256, 0, stream>>>(z, lam, theta, VT);
  tf_ft<<<dim3(LDPC_N / 256, BB / 32), 256, 0, stream>>>(F, FT);
  k1_spmm<<<LDPC_N / 8, 512, 0, stream>>>(VT, FT, colcnt, csc_c, lambda_W,
                                          Lambda_A, miu, alpha, UT);
  tu_ut<<<dim3(LDPC_N / 32, BB / 32), 256, 0, stream>>>(UT, out_u);
  k2_spmm<<<M_A / K2I, 512, 0, stream>>>(UT, z, lam, theta, relax, acc,
                                         rowcnt, csr_c, out_z, out_lam);
  k3a_solve<<<BB, 64, 0, stream>>>(out_u, real_Xp, imag_Xp, sigma2_I, YYp,
                                   lambda_W, factor, acc_new_i,
                                   WcG, out_lw, out_accnew);
  k3b_fnew<<<BB, 256, 0, stream>>>(out_u, Y, WcG, lambda_W, factor, out_F);
}

// Round 5
// 508.417 us; speedup vs baseline: 1.5625x; 1.1468x over previous
//
#include <hip/hip_runtime.h>
#include <math.h>

#define BB 512
#define NT 8
#define NR 8
#define LDIM 256
#define LP 16
#define LDPC_N 4096
#define M_A 12288
#define COLCAP 128
#define ROWCAP 64
#define K2I 16
#define SQ2 1.41421356237309515f
#define INVSQ2 0.70710678118654752f

typedef unsigned short u16;
typedef unsigned int u32;

__device__ __forceinline__ float bflo(u32 u) { return __uint_as_float(u << 16); }
__device__ __forceinline__ float bfhi(u32 u) { return __uint_as_float(u & 0xffff0000u); }
__device__ __forceinline__ u16 f2bf(float f) {
  u32 b = __float_as_uint(f);
  return (u16)((b + 0x7fffu + ((b >> 16) & 1u)) >> 16);
}

// ---------------- build sparse index lists (contiguous per col/row) ----------------
__global__ __launch_bounds__(256) void build_sparse(
    const float* __restrict__ A, int* __restrict__ colcnt, int* __restrict__ rowcnt,
    int* __restrict__ csc_c, int* __restrict__ csr_c) {
  const long long total4 = (long long)M_A * LDPC_N / 4;
  long long stride = (long long)gridDim.x * blockDim.x;
  for (long long t = (long long)blockIdx.x * blockDim.x + threadIdx.x; t < total4; t += stride) {
    float4 a = ((const float4*)A)[t];
    long long base = t * 4;
    float av[4] = {a.x, a.y, a.z, a.w};
#pragma unroll
    for (int l = 0; l < 4; l++) {
      if (av[l] != 0.0f) {
        long long lin = base + l;
        int i = (int)(lin >> 12);
        int j = (int)(lin & 4095);
        int sc = atomicAdd(&colcnt[j], 1);
        if (sc < COLCAP) csc_c[j * COLCAP + sc] = i;
        int sr = atomicAdd(&rowcnt[i], 1);
        if (sr < ROWCAP) csr_c[i * ROWCAP + sr] = j;
      }
    }
  }
}

// ---------------- T1+TF fused: VT[i][b] (bf16), FT[j][b] (bf16) ----------------
__global__ __launch_bounds__(256) void t1tf(
    const float* __restrict__ z, const float* __restrict__ lam,
    const float* __restrict__ theta, const float* __restrict__ F,
    u16* __restrict__ VT, u16* __restrict__ FT) {
  __shared__ float tile[256 * 33];
  int bx = blockIdx.x;
  if (bx < 6144) {  // t1: VT[i][b] = theta[i]-z[b][i]-lam[b][i]
    int i0 = (bx % 384) * 32, b0 = (bx / 384) * 32;
    {
      int il = threadIdx.x & 31, bq = threadIdx.x >> 5;
      float th = theta[i0 + il];
#pragma unroll
      for (int m = 0; m < 4; m++) {
        int bl = bq + m * 8;
        size_t off = (size_t)(b0 + bl) * M_A + i0 + il;
        tile[il * 33 + bl] = th - z[off] - lam[off];
      }
    }
    __syncthreads();
    {
      int bl = threadIdx.x & 31, iq = threadIdx.x >> 5;
#pragma unroll
      for (int m = 0; m < 4; m++) {
        int il = iq + m * 8;
        VT[(size_t)(i0 + il) * BB + b0 + bl] = f2bf(tile[il * 33 + bl]);
      }
    }
  } else {  // tf: FT[j][b], j = ld*16 + nt*2 + p, from F[b][p*8+nt][ld]
    int t = bx - 6144;
    int j0 = (t & 15) * 256, b0 = (t >> 4) * 32;
    int ld0 = j0 >> 4;
    int cc = threadIdx.x >> 4, dd = threadIdx.x & 15;
    int jl = dd * 16 + ((cc & 7) << 1) + (cc >> 3);
    for (int m = 0; m < 32; m++) {
      tile[jl * 33 + m] = F[(size_t)(b0 + m) * 4096 + cc * 256 + ld0 + dd];
    }
    __syncthreads();
    int bl = threadIdx.x & 31, jq = threadIdx.x >> 5;
    for (int jj = 0; jj < 32; jj++) {
      int jlo = jq * 32 + jj;
      FT[(size_t)(j0 + jlo) * BB + b0 + bl] = f2bf(tile[jlo * 33 + bl]);
    }
  }
}

// ---------------- K1: UT[j][b] bf16; 256 thr x 2 batches; 4 cols/block ----------------
__global__ __launch_bounds__(256) void k1_spmm(
    const u16* __restrict__ VT, const u16* __restrict__ FT,
    const int* __restrict__ colcnt, const int* __restrict__ csc_c,
    const float* __restrict__ lambda_W, const float* __restrict__ Lambda_A,
    const float* __restrict__ miu_p, const float* __restrict__ alpha_p,
    u16* __restrict__ UT) {
  __shared__ int idx[4 * COLCAP];
  __shared__ int cnts[4];
  __shared__ float lamA[4];
  int j0 = blockIdx.x * 4;
  int t = threadIdx.x;  // handles batches 2t, 2t+1
  for (int s = t; s < 4 * COLCAP; s += 256) idx[s] = csc_c[j0 * COLCAP + s];
  if (t < 4) {
    cnts[t] = min(colcnt[j0 + t], COLCAP);
    lamA[t] = Lambda_A[j0 + t];
  }
  __syncthreads();
  float miu = miu_p[0], alpha = alpha_p[0];
  float2 lw2 = *(const float2*)&lambda_W[2 * t];
#pragma unroll
  for (int c = 0; c < 4; c++) {
    int cnt = cnts[c];
    const int* ic = &idx[c * COLCAP];
    float a0 = 0.0f, a1 = 0.0f;
    int k = 0;
    for (; k + 3 < cnt; k += 4) {
      int4 i4 = *(const int4*)&ic[k];
      u32 w0 = *(const u32*)&VT[(size_t)i4.x * BB + 2 * t];
      u32 w1 = *(const u32*)&VT[(size_t)i4.y * BB + 2 * t];
      u32 w2 = *(const u32*)&VT[(size_t)i4.z * BB + 2 * t];
      u32 w3 = *(const u32*)&VT[(size_t)i4.w * BB + 2 * t];
      a0 += (bflo(w0) + bflo(w1)) + (bflo(w2) + bflo(w3));
      a1 += (bfhi(w0) + bfhi(w1)) + (bfhi(w2) + bfhi(w3));
    }
    for (; k < cnt; k++) {
      u32 w = *(const u32*)&VT[(size_t)ic[k] * BB + 2 * t];
      a0 += bflo(w);
      a1 += bfhi(w);
    }
    int j = j0 + c;
    u32 rr = *(const u32*)&FT[(size_t)j * BB + 2 * t];
    float res0 = bflo(rr), res1 = bfhi(rr);
    float q0 = miu * a0 + 2.0f * lw2.x - 2.0f * SQ2 * res0 - alpha;
    float q1 = miu * a1 + 2.0f * lw2.y - 2.0f * SQ2 * res1 - alpha;
    float w0 = 1.0f / (miu * lamA[c] + 4.0f * lw2.x - 2.0f * alpha);
    float w1 = 1.0f / (miu * lamA[c] + 4.0f * lw2.y - 2.0f * alpha);
    float u0 = fminf(fmaxf(q0 * w0, 0.0f), 1.0f);
    float u1 = fminf(fmaxf(q1 * w1, 0.0f), 1.0f);
    u32 packed = (u32)f2bf(u0) | ((u32)f2bf(u1) << 16);
    *(u32*)&UT[(size_t)j * BB + 2 * t] = packed;
  }
}

// ---------------- TU: out_u[b][j] = f32(UT[j][b]) ----------------
__global__ __launch_bounds__(256) void tu_ut(const u16* __restrict__ UT, float* __restrict__ out_u) {
  __shared__ float tile[32 * 33];
  int j0 = blockIdx.x * 32, b0 = blockIdx.y * 32;
  {
    int bl = threadIdx.x & 31, jq = threadIdx.x >> 5;
#pragma unroll
    for (int m = 0; m < 4; m++) {
      int jl = jq + m * 8;
      tile[jl * 33 + bl] = bflo((u32)UT[(size_t)(j0 + jl) * BB + b0 + bl]);
    }
  }
  __syncthreads();
  {
    int jl = threadIdx.x & 31, bq = threadIdx.x >> 5;
#pragma unroll
    for (int m = 0; m < 4; m++) {
      int bl = bq + m * 8;
      out_u[(size_t)(b0 + bl) * LDPC_N + j0 + jl] = tile[jl * 33 + bl];
    }
  }
}

// ---------------- K2: z / lambda1 update; 256 thr x 2 batches ----------------
__global__ __launch_bounds__(256) void k2_spmm(
    const u16* __restrict__ UT, const float* __restrict__ z_old,
    const float* __restrict__ lam_old, const float* __restrict__ theta,
    const float* __restrict__ relax_p, const float* __restrict__ acc_p,
    const int* __restrict__ rowcnt, const int* __restrict__ csr_c,
    float* __restrict__ out_z, float* __restrict__ out_lam) {
  __shared__ int idx[K2I * ROWCAP];
  __shared__ int cnts[K2I];
  __shared__ float ths[K2I];
  __shared__ float ssum[K2I * 514];
  int i0 = blockIdx.x * K2I;
  int t = threadIdx.x;
  for (int s = t; s < K2I * ROWCAP; s += 256) idx[s] = csr_c[i0 * ROWCAP + s];
  if (t < K2I) {
    cnts[t] = min(rowcnt[i0 + t], ROWCAP);
    ths[t] = theta[i0 + t];
  }
  __syncthreads();
  for (int r = 0; r < K2I; r++) {
    int cnt = cnts[r];
    const int* ir = &idx[r * ROWCAP];
    float s0 = 0.0f, s1 = 0.0f;
    int k = 0;
    for (; k + 3 < cnt; k += 4) {
      int4 i4 = *(const int4*)&ir[k];
      u32 w0 = *(const u32*)&UT[(size_t)i4.x * BB + 2 * t];
      u32 w1 = *(const u32*)&UT[(size_t)i4.y * BB + 2 * t];
      u32 w2 = *(const u32*)&UT[(size_t)i4.z * BB + 2 * t];
      u32 w3 = *(const u32*)&UT[(size_t)i4.w * BB + 2 * t];
      s0 += (bflo(w0) + bflo(w1)) + (bflo(w2) + bflo(w3));
      s1 += (bfhi(w0) + bfhi(w1)) + (bfhi(w2) + bfhi(w3));
    }
    for (; k < cnt; k++) {
      u32 w = *(const u32*)&UT[(size_t)ir[k] * BB + 2 * t];
      s0 += bflo(w);
      s1 += bfhi(w);
    }
    *(float2*)&ssum[r * 514 + 2 * t] = make_float2(s0, s1);
  }
  __syncthreads();
  float relax = relax_p[0], acc = acc_p[0];
  int iw = t & 15, bq = t >> 4;  // bq 0..15
  float th = ths[iw];
  for (int p = 0; p < 32; p++) {
    int b = p * 16 + bq;
    size_t off = (size_t)b * M_A + i0 + iw;
    float zo = z_old[off];
    float lo = lam_old[off];
    float s = ssum[iw * 514 + b];
    float ztemp = th - relax * s - (1.0f - relax) * (th - zo) - lo;
    float zn = fmaxf(ztemp, 0.0f);
    float ln = zn - ztemp;
    out_z[off] = zn + acc * (zn - zo);
    out_lam[off] = ln + acc * (ln - lo);
  }
}

// ---------------- K3: per-batch MMSE solve + F_new (monolithic, 256 thr, barriered) ----------------
#define RL(i, j) Rs[(i) * 17 + (j)]
__global__ __launch_bounds__(256) void k3_mmse(
    const float* __restrict__ u, const float* __restrict__ real_Xp,
    const float* __restrict__ imag_Xp, const float* __restrict__ sigma2_I,
    const float* __restrict__ YYp, const float* __restrict__ Y,
    const float* __restrict__ lambda_W, const float* __restrict__ factor_p,
    const float* __restrict__ acc_new_in,
    float* __restrict__ out_lw, float* __restrict__ out_F, float* __restrict__ out_accnew) {
  __shared__ float XX[16][545];
  __shared__ float yy[8 * 545];
  __shared__ float Rs[16 * 17];
  __shared__ float invd[16];
  __shared__ float Tm[16][8];
  __shared__ float Wcs[256];
  __shared__ float Gs[256];
  int b = blockIdx.x;
  int tid = threadIdx.x;

  // build XX from u (float4 = rows (2k,2k+1) x (re,im) at col ld)
  const float4* u4 = (const float4*)(u + (size_t)b * LDPC_N);
  for (int m = tid; m < 1024; m += 256) {
    float4 q = u4[m];
    int ld = m >> 2;
    int nt = (2 * m) & 7;  // even
    float vr0 = (1.0f - 2.0f * q.x) * INVSQ2;
    float vi0 = (1.0f - 2.0f * q.y) * INVSQ2;
    float vr1 = (1.0f - 2.0f * q.z) * INVSQ2;
    float vi1 = (1.0f - 2.0f * q.w) * INVSQ2;
    XX[nt][ld] = vr0;        XX[nt][272 + ld] = vi0;
    XX[8 + nt][ld] = -vi0;   XX[8 + nt][272 + ld] = vr0;
    XX[nt + 1][ld] = vr1;    XX[nt + 1][272 + ld] = vi1;
    XX[9 + nt][ld] = -vi1;   XX[9 + nt][272 + ld] = vr1;
  }
  if (tid < 128) {
    int r = tid >> 4, pc = tid & 15;
    float vr = real_Xp[(size_t)b * 128 + tid];
    float vi = imag_Xp[(size_t)b * 128 + tid];
    XX[r][256 + pc] = vr;      XX[r][528 + pc] = vi;
    XX[8 + r][256 + pc] = -vi; XX[8 + r][528 + pc] = vr;
  }
  {
    const float4* y4 = (const float4*)(YYp + (size_t)b * NR * 544);
    for (int s = tid; s < 1088; s += 256) {
      float4 v = y4[s];
      int lin = s * 4;
      int row = lin / 544, col = lin % 544;
      float* d = &yy[row * 545 + col];
      d[0] = v.x; d[1] = v.y; d[2] = v.z; d[3] = v.w;
    }
  }
  __syncthreads();

  // dots: 136 R-triangle + 128 T entries, one task per thread
  for (int p = tid; p < 264; p += 256) {
    if (p < 136) {
      int i = 0;
      while ((i + 1) * (i + 2) / 2 <= p) i++;
      int j = p - i * (i + 1) / 2;
      float s = 0.0f;
      for (int k = 0; k < 544; k++) s += XX[i][k] * XX[j][k];
      RL(i, j) = s + sigma2_I[(size_t)b * 256 + i * 16 + j];
    } else {
      int q = p - 136;
      int i = q >> 3, m = q & 7;
      float s = 0.0f;
      for (int k = 0; k < 544; k++) s += XX[i][k] * yy[m * 545 + k];
      Tm[i][m] = s;
    }
  }
  __syncthreads();

  // Cholesky with full-block barriers (round-4's barrier-free version raced:
  // compiler may cache/reorder LDS accesses across divergent lanes without barriers)
  for (int k = 0; k < 16; k++) {
    if (tid == 0) {
      float d = sqrtf(fmaxf(RL(k, k), 1e-30f));
      RL(k, k) = d;
      invd[k] = 1.0f / d;
    }
    __syncthreads();
    if (tid > k && tid < 16) RL(tid, k) *= invd[k];
    __syncthreads();
    {
      int i = tid >> 4, j = tid & 15;
      if (i > k && j > k && j <= i) RL(i, j) -= RL(i, k) * RL(j, k);
    }
    __syncthreads();
  }

  // triangular solves: 8 lanes own one RHS column each, fully in registers.
  // Safe: all LDS inputs (RL, invd, Tm) finalized before the barrier above;
  // writes go to disjoint Tm slots, republished by the barrier below.
  if (tid < 8) {
    int m = tid;
    float yv[16], wv[16];
#pragma unroll
    for (int r = 0; r < 16; r++) {
      float s = Tm[r][m];
      for (int c = 0; c < r; c++) s -= RL(r, c) * yv[c];
      yv[r] = s * invd[r];
    }
#pragma unroll
    for (int r = 15; r >= 0; r--) {
      float s = yv[r];
      for (int c = r + 1; c < 16; c++) s -= RL(c, r) * wv[c];
      wv[r] = s * invd[r];
    }
#pragma unroll
    for (int r = 0; r < 16; r++) Tm[r][m] = wv[r];
  }
  __syncthreads();

  // Wc = WT = [[rW, iW],[-iW, rW]]
  {
    int i = tid >> 4, j = tid & 15;
    int ii = i & 7, jj = j & 7;
    float val;
    if (i < 8) val = (j < 8) ? Tm[ii][jj] : Tm[8 + ii][jj];
    else       val = (j < 8) ? -Tm[8 + ii][jj] : Tm[ii][jj];
    Wcs[tid] = val;
  }
  __syncthreads();
  {
    int i = tid >> 4, j = tid & 15;
    float s = 0.0f;
#pragma unroll
    for (int k = 0; k < 16; k++) s += Wcs[i * 16 + k] * Wcs[j * 16 + k];
    Gs[tid] = s;
  }
  __syncthreads();

  // F_new epilogue: thread = ld column
  float lw_new = factor_p[0] * lambda_W[b];
  {
    int ld = tid;
    float Xv[16], Yv[16];
#pragma unroll
    for (int c = 0; c < 8; c++) {
      Xv[c] = XX[c][ld];
      Xv[8 + c] = XX[c][272 + ld];
    }
    const float* Yb = Y + (size_t)b * 16 * LDIM;
#pragma unroll
    for (int c = 0; c < 16; c++) Yv[c] = Yb[c * LDIM + ld];
    float* Fb = out_F + (size_t)b * 16 * LDIM;
    for (int r = 0; r < 16; r++) {
      float s = lw_new * Xv[r];
#pragma unroll
      for (int c = 0; c < 16; c++) s += Wcs[r * 16 + c] * Yv[c] - Gs[r * 16 + c] * Xv[c];
      Fb[r * LDIM + ld] = s;
    }
  }
  if (tid == 0) {
    out_lw[b] = lw_new;
    out_accnew[b] = acc_new_in[b];
  }
}

extern "C" void kernel_launch(void* const* d_in, const int* in_sizes, int n_in,
                              void* d_out, int out_size, void* d_ws, size_t ws_size,
                              hipStream_t stream) {
  const float* sigma2_I  = (const float*)d_in[0];
  const float* Y         = (const float*)d_in[1];
  const float* YYp       = (const float*)d_in[2];
  const float* real_Xp   = (const float*)d_in[3];
  const float* imag_Xp   = (const float*)d_in[4];
  const float* lambda_W  = (const float*)d_in[5];
  const float* F         = (const float*)d_in[6];
  const float* z         = (const float*)d_in[8];
  const float* lam       = (const float*)d_in[9];
  const float* acc_new_i = (const float*)d_in[10];
  const float* A         = (const float*)d_in[11];
  const float* theta     = (const float*)d_in[12];
  const float* Lambda_A  = (const float*)d_in[13];
  const float* miu       = (const float*)d_in[14];
  const float* alpha     = (const float*)d_in[15];
  const float* factor    = (const float*)d_in[16];
  const float* relax     = (const float*)d_in[17];
  const float* acc       = (const float*)d_in[18];

  float* out = (float*)d_out;
  float* out_lw     = out;
  float* out_F      = out_lw + BB;
  float* out_u      = out_F + (size_t)BB * 2 * NT * LDIM;
  float* out_z      = out_u + (size_t)BB * LDPC_N;
  float* out_lam    = out_z + (size_t)BB * M_A;
  float* out_accnew = out_lam + (size_t)BB * M_A;

  // bf16 temporaries aliased into not-yet-final d_out regions (stream order safe):
  u16* VT = (u16*)out_z;    // 12.6 MB < 25 MB; consumed by k1, overwritten by k2
  u16* FT = (u16*)out_lam;  //  4.2 MB < 25 MB; consumed by k1, overwritten by k2
  u16* UT = (u16*)out_F;    //  4.2 MB < 8.4 MB; consumed by tu/k2, overwritten by k3

  int* ws = (int*)d_ws;
  int* colcnt = ws;                       // 4096
  int* rowcnt = colcnt + LDPC_N;          // 12288
  int* csc_c  = rowcnt + M_A;             // COLCAP*4096
  int* csr_c  = csc_c + COLCAP * LDPC_N;  // ROWCAP*12288

  hipMemsetAsync(colcnt, 0, (LDPC_N + M_A) * sizeof(int), stream);
  build_sparse<<<2048, 256, 0, stream>>>(A, colcnt, rowcnt, csc_c, csr_c);
  t1tf<<<6400, 256, 0, stream>>>(z, lam, theta, F, VT, FT);
  k1_spmm<<<LDPC_N / 4, 256, 0, stream>>>(VT, FT, colcnt, csc_c, lambda_W,
                                          Lambda_A, miu, alpha, UT);
  tu_ut<<<dim3(LDPC_N / 32, BB / 32), 256, 0, stream>>>(UT, out_u);
  k2_spmm<<<M_A / K2I, 256, 0, stream>>>(UT, z, lam, theta, relax, acc,
                                         rowcnt, csr_c, out_z, out_lam);
  k3_mmse<<<BB, 256, 0, stream>>>(out_u, real_Xp, imag_Xp, sigma2_I, YYp, Y,
                                  lambda_W, factor, acc_new_i,
                                  out_lw, out_F, out_accnew);
}

// Round 6
// 505.834 us; speedup vs baseline: 1.5704x; 1.0051x over previous
//
#include <hip/hip_runtime.h>
#include <math.h>

#define BB 512
#define NT 8
#define NR 8
#define LDIM 256
#define LP 16
#define LDPC_N 4096
#define M_A 12288
#define COLCAP 128
#define ROWCAP 64
#define SQ2 1.41421356237309515f
#define INVSQ2 0.70710678118654752f

typedef unsigned short u16;
typedef unsigned int u32;

__device__ __forceinline__ float bflo(u32 u) { return __uint_as_float(u << 16); }
__device__ __forceinline__ float bfhi(u32 u) { return __uint_as_float(u & 0xffff0000u); }
__device__ __forceinline__ u16 f2bf(float f) {
  u32 b = __float_as_uint(f);
  return (u16)((b + 0x7fffu + ((b >> 16) & 1u)) >> 16);
}
__device__ __forceinline__ void add8(const uint4& v, float* a) {
  a[0] += bflo(v.x); a[1] += bfhi(v.x);
  a[2] += bflo(v.y); a[3] += bfhi(v.y);
  a[4] += bflo(v.z); a[5] += bfhi(v.z);
  a[6] += bflo(v.w); a[7] += bfhi(v.w);
}

// ---------------- build sparse index lists (contiguous per col/row) ----------------
__global__ __launch_bounds__(256) void build_sparse(
    const float* __restrict__ A, int* __restrict__ colcnt, int* __restrict__ rowcnt,
    int* __restrict__ csc_c, int* __restrict__ csr_c) {
  const long long total4 = (long long)M_A * LDPC_N / 4;
  long long stride = (long long)gridDim.x * blockDim.x;
  for (long long t = (long long)blockIdx.x * blockDim.x + threadIdx.x; t < total4; t += stride) {
    float4 a = ((const float4*)A)[t];
    long long base = t * 4;
    float av[4] = {a.x, a.y, a.z, a.w};
#pragma unroll
    for (int l = 0; l < 4; l++) {
      if (av[l] != 0.0f) {
        long long lin = base + l;
        int i = (int)(lin >> 12);
        int j = (int)(lin & 4095);
        int sc = atomicAdd(&colcnt[j], 1);
        if (sc < COLCAP) csc_c[j * COLCAP + sc] = i;
        int sr = atomicAdd(&rowcnt[i], 1);
        if (sr < ROWCAP) csr_c[i * ROWCAP + sr] = j;
      }
    }
  }
}

// ---------------- T1+TF fused: VT[i][b] (bf16), FT[j][b] (bf16) ----------------
__global__ __launch_bounds__(256) void t1tf(
    const float* __restrict__ z, const float* __restrict__ lam,
    const float* __restrict__ theta, const float* __restrict__ F,
    u16* __restrict__ VT, u16* __restrict__ FT) {
  __shared__ float tile[256 * 33];
  int bx = blockIdx.x;
  if (bx < 6144) {  // t1: VT[i][b] = theta[i]-z[b][i]-lam[b][i]
    int i0 = (bx % 384) * 32, b0 = (bx / 384) * 32;
    {
      int il = threadIdx.x & 31, bq = threadIdx.x >> 5;
      float th = theta[i0 + il];
#pragma unroll
      for (int m = 0; m < 4; m++) {
        int bl = bq + m * 8;
        size_t off = (size_t)(b0 + bl) * M_A + i0 + il;
        tile[il * 33 + bl] = th - z[off] - lam[off];
      }
    }
    __syncthreads();
    {
      int bl = threadIdx.x & 31, iq = threadIdx.x >> 5;
#pragma unroll
      for (int m = 0; m < 4; m++) {
        int il = iq + m * 8;
        VT[(size_t)(i0 + il) * BB + b0 + bl] = f2bf(tile[il * 33 + bl]);
      }
    }
  } else {  // tf: FT[j][b], j = ld*16 + nt*2 + p, from F[b][p*8+nt][ld]
    int t = bx - 6144;
    int j0 = (t & 15) * 256, b0 = (t >> 4) * 32;
    int ld0 = j0 >> 4;
    int cc = threadIdx.x >> 4, dd = threadIdx.x & 15;
    int jl = dd * 16 + ((cc & 7) << 1) + (cc >> 3);
    for (int m = 0; m < 32; m++) {
      tile[jl * 33 + m] = F[(size_t)(b0 + m) * 4096 + cc * 256 + ld0 + dd];
    }
    __syncthreads();
    int bl = threadIdx.x & 31, jq = threadIdx.x >> 5;
    for (int jj = 0; jj < 32; jj++) {
      int jlo = jq * 32 + jj;
      FT[(size_t)(j0 + jlo) * BB + b0 + bl] = f2bf(tile[jlo * 33 + bl]);
    }
  }
}

// ---------------- K1: lane owns 8 batches; wave owns a column; 16B gathers ----------------
__global__ __launch_bounds__(256) void k1_spmm(
    const u16* __restrict__ VT, const u16* __restrict__ FT,
    const int* __restrict__ colcnt, const int* __restrict__ csc_c,
    const float* __restrict__ lambda_W, const float* __restrict__ Lambda_A,
    const float* __restrict__ miu_p, const float* __restrict__ alpha_p,
    u16* __restrict__ UT) {
  __shared__ int idx[4 * COLCAP];
  __shared__ float lwS[512];
  __shared__ int cnts[4];
  __shared__ float lamA[4];
  int j0 = blockIdx.x * 4;
  int t = threadIdx.x;
  for (int s = t; s < 4 * COLCAP; s += 256) idx[s] = csc_c[j0 * COLCAP + s];
  for (int s = t; s < 512; s += 256) lwS[s] = lambda_W[s];
  if (t < 4) {
    cnts[t] = min(colcnt[j0 + t], COLCAP);
    lamA[t] = Lambda_A[j0 + t];
  }
  __syncthreads();
  int w = t >> 6, l = t & 63;
  int j = j0 + w;
  int boff = 8 * l;
  int cnt = cnts[w];
  const int* ic = &idx[w * COLCAP];
  float av[8] = {0, 0, 0, 0, 0, 0, 0, 0};
  int k = 0;
  for (; k + 1 < cnt; k += 2) {
    uint4 va = *(const uint4*)&VT[(size_t)ic[k] * BB + boff];
    uint4 vb = *(const uint4*)&VT[(size_t)ic[k + 1] * BB + boff];
    add8(va, av);
    add8(vb, av);
  }
  if (k < cnt) {
    uint4 va = *(const uint4*)&VT[(size_t)ic[k] * BB + boff];
    add8(va, av);
  }
  float miu = miu_p[0], alpha = alpha_p[0];
  float la = lamA[w];
  uint4 fr = *(const uint4*)&FT[(size_t)j * BB + boff];
  float res[8] = {bflo(fr.x), bfhi(fr.x), bflo(fr.y), bfhi(fr.y),
                  bflo(fr.z), bfhi(fr.z), bflo(fr.w), bfhi(fr.w)};
  u32 pk[4];
#pragma unroll
  for (int e = 0; e < 4; e++) {
    float lw0 = lwS[boff + 2 * e], lw1 = lwS[boff + 2 * e + 1];
    float q0 = miu * av[2 * e] + 2.0f * lw0 - 2.0f * SQ2 * res[2 * e] - alpha;
    float q1 = miu * av[2 * e + 1] + 2.0f * lw1 - 2.0f * SQ2 * res[2 * e + 1] - alpha;
    float w0 = 1.0f / (miu * la + 4.0f * lw0 - 2.0f * alpha);
    float w1 = 1.0f / (miu * la + 4.0f * lw1 - 2.0f * alpha);
    float u0 = fminf(fmaxf(q0 * w0, 0.0f), 1.0f);
    float u1 = fminf(fmaxf(q1 * w1, 0.0f), 1.0f);
    pk[e] = (u32)f2bf(u0) | ((u32)f2bf(u1) << 16);
  }
  *(uint4*)&UT[(size_t)j * BB + boff] = make_uint4(pk[0], pk[1], pk[2], pk[3]);
}

// ---------------- fused3: tu (out_u) + k2 (z/lam) + k3 (MMSE+F_new), independent parts ----------------
__global__ __launch_bounds__(256) void fused3(
    const u16* __restrict__ UT, const float* __restrict__ z_old,
    const float* __restrict__ lam_old, const float* __restrict__ theta,
    const float* __restrict__ relax_p, const float* __restrict__ acc_p,
    const int* __restrict__ rowcnt, const int* __restrict__ csr_c,
    float* __restrict__ out_u, float* __restrict__ out_z, float* __restrict__ out_lam,
    const float* __restrict__ real_Xp, const float* __restrict__ imag_Xp,
    const float* __restrict__ sigma2_I, const float* __restrict__ YYp,
    const float* __restrict__ Y, const float* __restrict__ lambda_W,
    const float* __restrict__ factor_p, const float* __restrict__ acc_new_in,
    float* __restrict__ out_lw, float* __restrict__ out_F, float* __restrict__ out_accnew) {
  __shared__ float smem[9856];  // 38.5 KB, re-cast per role
  int bidx = blockIdx.x;
  int tid = threadIdx.x;

  if (bidx < 2048) {
    // ---- tu: out_u[b][j] = f32(UT[j][b]) ----
    float* tile = smem;  // 32*33
    int j0 = (bidx & 127) * 32, b0 = (bidx >> 7) * 32;
    {
      int bl = tid & 31, jq = tid >> 5;
#pragma unroll
      for (int m = 0; m < 4; m++) {
        int jl = jq + m * 8;
        tile[jl * 33 + bl] = bflo((u32)UT[(size_t)(j0 + jl) * BB + b0 + bl]);
      }
    }
    __syncthreads();
    {
      int jl = tid & 31, bq = tid >> 5;
#pragma unroll
      for (int m = 0; m < 4; m++) {
        int bl = bq + m * 8;
        out_u[(size_t)(b0 + bl) * LDPC_N + j0 + jl] = tile[jl * 33 + bl];
      }
    }
  } else if (bidx < 2816) {
    // ---- k2: z/lambda1 update; lane owns 8 batches, wave owns 4 rows ----
    int* idx = (int*)smem;                 // [16][64]
    int* cnts = idx + 1024;                // 16
    float* ths = (float*)(idx + 1040);     // 16
    float* ssum = (float*)(idx + 1056);    // [16][520]
    int i0 = (bidx - 2048) * 16;
    for (int s = tid; s < 1024; s += 256) idx[s] = csr_c[i0 * ROWCAP + s];
    if (tid < 16) {
      cnts[tid] = min(rowcnt[i0 + tid], ROWCAP);
      ths[tid] = theta[i0 + tid];
    }
    __syncthreads();
    int w = tid >> 6, l = tid & 63, boff = 8 * l;
    for (int rr = 0; rr < 4; rr++) {
      int r = w * 4 + rr;
      int cnt = cnts[r];
      const int* ir = &idx[r * ROWCAP];
      float s[8] = {0, 0, 0, 0, 0, 0, 0, 0};
      int k = 0;
      for (; k + 1 < cnt; k += 2) {
        uint4 va = *(const uint4*)&UT[(size_t)ir[k] * BB + boff];
        uint4 vb = *(const uint4*)&UT[(size_t)ir[k + 1] * BB + boff];
        add8(va, s);
        add8(vb, s);
      }
      if (k < cnt) {
        uint4 va = *(const uint4*)&UT[(size_t)ir[k] * BB + boff];
        add8(va, s);
      }
      *(float4*)&ssum[r * 520 + boff] = make_float4(s[0], s[1], s[2], s[3]);
      *(float4*)&ssum[r * 520 + boff + 4] = make_float4(s[4], s[5], s[6], s[7]);
    }
    __syncthreads();
    float relax = relax_p[0], acc = acc_p[0];
    int iw = tid & 15, bq = tid >> 4;
    float th = ths[iw];
    for (int p = 0; p < 32; p++) {
      int b = p * 16 + bq;
      size_t off = (size_t)b * M_A + i0 + iw;
      float zo = z_old[off];
      float lo = lam_old[off];
      float s = ssum[iw * 520 + b];
      float ztemp = th - relax * s - (1.0f - relax) * (th - zo) - lo;
      float zn = fmaxf(ztemp, 0.0f);
      float ln = zn - ztemp;
      out_z[off] = zn + acc * (zn - zo);
      out_lam[off] = ln + acc * (ln - lo);
    }
  } else {
    // ---- k3: per-batch MMSE solve + F_new ----
    float* XX = smem;              // [16][545]
    float* Rs = XX + 8720;         // [16][17]
    float* invd = Rs + 272;        // 16
    float* Tm = invd + 16;         // [16][8]
    float* Wcs = Tm + 128;         // 256
    float* Gs = Wcs + 256;         // 256
#define XXA(r, c) XX[(r) * 545 + (c)]
#define RLp(i, j) Rs[(i) * 17 + (j)]
    int b = bidx - 2816;

    // XX from UT (bit-identical to out_u = bflo(UT))
    for (int m = tid; m < 1024; m += 256) {
      int ld = m >> 2;
      int nt = (2 * m) & 7;
      int j4 = 4 * m;
      float q0 = bflo((u32)UT[(size_t)(j4 + 0) * BB + b]);
      float q1 = bflo((u32)UT[(size_t)(j4 + 1) * BB + b]);
      float q2 = bflo((u32)UT[(size_t)(j4 + 2) * BB + b]);
      float q3 = bflo((u32)UT[(size_t)(j4 + 3) * BB + b]);
      float vr0 = (1.0f - 2.0f * q0) * INVSQ2, vi0 = (1.0f - 2.0f * q1) * INVSQ2;
      float vr1 = (1.0f - 2.0f * q2) * INVSQ2, vi1 = (1.0f - 2.0f * q3) * INVSQ2;
      XXA(nt, ld) = vr0;          XXA(nt, 272 + ld) = vi0;
      XXA(8 + nt, ld) = -vi0;     XXA(8 + nt, 272 + ld) = vr0;
      XXA(nt + 1, ld) = vr1;      XXA(nt + 1, 272 + ld) = vi1;
      XXA(9 + nt, ld) = -vi1;     XXA(9 + nt, 272 + ld) = vr1;
    }
    if (tid < 128) {
      int r = tid >> 4, pc = tid & 15;
      float vr = real_Xp[(size_t)b * 128 + tid];
      float vi = imag_Xp[(size_t)b * 128 + tid];
      XXA(r, 256 + pc) = vr;       XXA(r, 528 + pc) = vi;
      XXA(8 + r, 256 + pc) = -vi;  XXA(8 + r, 528 + pc) = vr;
    }
    __syncthreads();

    // dots: 136 R-triangle (LDS) + 128 T entries (YYp direct, L2-resident)
    for (int p = tid; p < 264; p += 256) {
      if (p < 136) {
        int i = 0;
        while ((i + 1) * (i + 2) / 2 <= p) i++;
        int jj = p - i * (i + 1) / 2;
        float s = 0.0f;
        for (int k = 0; k < 544; k++) s += XXA(i, k) * XXA(jj, k);
        RLp(i, jj) = s + sigma2_I[(size_t)b * 256 + i * 16 + jj];
      } else {
        int q = p - 136;
        int i = q >> 3, m = q & 7;
        const float* yb = YYp + (size_t)b * 4352 + m * 544;
        float s = 0.0f;
        for (int k = 0; k < 544; k++) s += XXA(i, k) * yb[k];
        Tm[i * 8 + m] = s;
      }
    }
    __syncthreads();

    // Cholesky (full-block barriers — round-4 lesson: no barrier-free LDS ordering)
    for (int k = 0; k < 16; k++) {
      if (tid == 0) {
        float d = sqrtf(fmaxf(RLp(k, k), 1e-30f));
        RLp(k, k) = d;
        invd[k] = 1.0f / d;
      }
      __syncthreads();
      if (tid > k && tid < 16) RLp(tid, k) *= invd[k];
      __syncthreads();
      {
        int i = tid >> 4, jj = tid & 15;
        if (i > k && jj > k && jj <= i) RLp(i, jj) -= RLp(i, k) * RLp(jj, k);
      }
      __syncthreads();
    }

    // triangular solves: 8 lanes, register-resident (inputs finalized pre-barrier)
    if (tid < 8) {
      int m = tid;
      float yv[16], wv[16];
#pragma unroll
      for (int r = 0; r < 16; r++) {
        float s = Tm[r * 8 + m];
        for (int c = 0; c < r; c++) s -= RLp(r, c) * yv[c];
        yv[r] = s * invd[r];
      }
#pragma unroll
      for (int r = 15; r >= 0; r--) {
        float s = yv[r];
        for (int c = r + 1; c < 16; c++) s -= RLp(c, r) * wv[c];
        wv[r] = s * invd[r];
      }
#pragma unroll
      for (int r = 0; r < 16; r++) Tm[r * 8 + m] = wv[r];
    }
    __syncthreads();

    // Wc = WT = [[rW, iW],[-iW, rW]]
    {
      int i = tid >> 4, jj = tid & 15;
      int ii = i & 7, jc = jj & 7;
      float val;
      if (i < 8) val = (jj < 8) ? Tm[ii * 8 + jc] : Tm[(8 + ii) * 8 + jc];
      else       val = (jj < 8) ? -Tm[(8 + ii) * 8 + jc] : Tm[ii * 8 + jc];
      Wcs[tid] = val;
    }
    __syncthreads();
    {
      int i = tid >> 4, jj = tid & 15;
      float s = 0.0f;
#pragma unroll
      for (int k = 0; k < 16; k++) s += Wcs[i * 16 + k] * Wcs[jj * 16 + k];
      Gs[tid] = s;
    }
    __syncthreads();

    // F_new epilogue: thread = ld column
    float lw_new = factor_p[0] * lambda_W[b];
    {
      int ld = tid;
      float Xv[16], Yv[16];
#pragma unroll
      for (int c = 0; c < 8; c++) {
        Xv[c] = XXA(c, ld);
        Xv[8 + c] = XXA(c, 272 + ld);
      }
      const float* Yb = Y + (size_t)b * 16 * LDIM;
#pragma unroll
      for (int c = 0; c < 16; c++) Yv[c] = Yb[c * LDIM + ld];
      float* Fb = out_F + (size_t)b * 16 * LDIM;
      for (int r = 0; r < 16; r++) {
        float s = lw_new * Xv[r];
#pragma unroll
        for (int c = 0; c < 16; c++) s += Wcs[r * 16 + c] * Yv[c] - Gs[r * 16 + c] * Xv[c];
        Fb[r * LDIM + ld] = s;
      }
    }
    if (tid == 0) {
      out_lw[b] = lw_new;
      out_accnew[b] = acc_new_in[b];
    }
#undef XXA
#undef RLp
  }
}

extern "C" void kernel_launch(void* const* d_in, const int* in_sizes, int n_in,
                              void* d_out, int out_size, void* d_ws, size_t ws_size,
                              hipStream_t stream) {
  const float* sigma2_I  = (const float*)d_in[0];
  const float* Y         = (const float*)d_in[1];
  const float* YYp       = (const float*)d_in[2];
  const float* real_Xp   = (const float*)d_in[3];
  const float* imag_Xp   = (const float*)d_in[4];
  const float* lambda_W  = (const float*)d_in[5];
  const float* F         = (const float*)d_in[6];
  const float* z         = (const float*)d_in[8];
  const float* lam       = (const float*)d_in[9];
  const float* acc_new_i = (const float*)d_in[10];
  const float* A         = (const float*)d_in[11];
  const float* theta     = (const float*)d_in[12];
  const float* Lambda_A  = (const float*)d_in[13];
  const float* miu       = (const float*)d_in[14];
  const float* alpha     = (const float*)d_in[15];
  const float* factor    = (const float*)d_in[16];
  const float* relax     = (const float*)d_in[17];
  const float* acc       = (const float*)d_in[18];

  float* out = (float*)d_out;
  float* out_lw     = out;
  float* out_F      = out_lw + BB;
  float* out_u      = out_F + (size_t)BB * 2 * NT * LDIM;
  float* out_z      = out_u + (size_t)BB * LDPC_N;
  float* out_lam    = out_z + (size_t)BB * M_A;
  float* out_accnew = out_lam + (size_t)BB * M_A;

  // VT/FT alias not-yet-final out regions (k1 reads them; fused3's k2 overwrites after).
  u16* VT = (u16*)out_z;
  u16* FT = (u16*)out_lam;

  int* ws = (int*)d_ws;
  int* colcnt = ws;                       // 4096
  int* rowcnt = colcnt + LDPC_N;          // 12288
  int* csc_c  = rowcnt + M_A;             // COLCAP*4096
  int* csr_c  = csc_c + COLCAP * LDPC_N;  // ROWCAP*12288
  u16* UT     = (u16*)(csr_c + ROWCAP * M_A);  // 4096*512 bf16 (4.2 MB) — NOT aliased to out_F
                                               // (k3 writes out_F while tu/k2/k3 read UT)

  hipMemsetAsync(colcnt, 0, (LDPC_N + M_A) * sizeof(int), stream);
  build_sparse<<<2048, 256, 0, stream>>>(A, colcnt, rowcnt, csc_c, csr_c);
  t1tf<<<6400, 256, 0, stream>>>(z, lam, theta, F, VT, FT);
  k1_spmm<<<LDPC_N / 4, 256, 0, stream>>>(VT, FT, colcnt, csc_c, lambda_W,
                                          Lambda_A, miu, alpha, UT);
  fused3<<<3328, 256, 0, stream>>>(UT, z, lam, theta, relax, acc, rowcnt, csr_c,
                                   out_u, out_z, out_lam,
                                   real_Xp, imag_Xp, sigma2_I, YYp, Y, lambda_W,
                                   factor, acc_new_i, out_lw, out_F, out_accnew);
}

// Round 7
// 488.593 us; speedup vs baseline: 1.6259x; 1.0353x over previous
//
#include <hip/hip_runtime.h>
#include <math.h>

#define BB 512
#define NT 8
#define NR 8
#define LDIM 256
#define LP 16
#define LDPC_N 4096
#define M_A 12288
#define COLCAP 128
#define ROWCAP 64
#define SQ2 1.41421356237309515f
#define INVSQ2 0.70710678118654752f

typedef unsigned short u16;
typedef unsigned int u32;

__device__ __forceinline__ float bflo(u32 u) { return __uint_as_float(u << 16); }
__device__ __forceinline__ float bfhi(u32 u) { return __uint_as_float(u & 0xffff0000u); }
__device__ __forceinline__ u16 f2bf(float f) {
  u32 b = __float_as_uint(f);
  return (u16)((b + 0x7fffu + ((b >> 16) & 1u)) >> 16);
}
__device__ __forceinline__ void add8(const uint4& v, float* a) {
  a[0] += bflo(v.x); a[1] += bfhi(v.x);
  a[2] += bflo(v.y); a[3] += bfhi(v.y);
  a[4] += bflo(v.z); a[5] += bfhi(v.z);
  a[6] += bflo(v.w); a[7] += bfhi(v.w);
}

// ---------------- prep: build sparse lists || VT transpose || FT transpose ----------------
__global__ __launch_bounds__(256) void prep(
    const float* __restrict__ A, int* __restrict__ colcnt, int* __restrict__ rowcnt,
    int* __restrict__ csc_c, int* __restrict__ csr_c,
    const float* __restrict__ z, const float* __restrict__ lam,
    const float* __restrict__ theta, const float* __restrict__ F,
    u16* __restrict__ VT, u16* __restrict__ FT) {
  __shared__ float tile[256 * 17];  // 17 KB; t1 uses 32*33 of it
  int bx = blockIdx.x;
  int tid = threadIdx.x;
  if (bx < 2048) {
    // ---- build: scan A, emit per-col/per-row index lists ----
    const long long total4 = (long long)M_A * LDPC_N / 4;
    const long long stride = 2048LL * 256LL;
    for (long long t = (long long)bx * 256 + tid; t < total4; t += stride) {
      float4 a = ((const float4*)A)[t];
      long long base = t * 4;
      float av[4] = {a.x, a.y, a.z, a.w};
#pragma unroll
      for (int l = 0; l < 4; l++) {
        if (av[l] != 0.0f) {
          long long lin = base + l;
          int i = (int)(lin >> 12);
          int j = (int)(lin & 4095);
          int sc = atomicAdd(&colcnt[j], 1);
          if (sc < COLCAP) csc_c[j * COLCAP + sc] = i;
          int sr = atomicAdd(&rowcnt[i], 1);
          if (sr < ROWCAP) csr_c[i * ROWCAP + sr] = j;
        }
      }
    }
  } else if (bx < 8192) {
    // ---- t1: VT[i][b] = theta[i]-z[b][i]-lam[b][i] (bf16) ----
    int bx2 = bx - 2048;
    int i0 = (bx2 % 384) * 32, b0 = (bx2 / 384) * 32;
    {
      int il = tid & 31, bq = tid >> 5;
      float th = theta[i0 + il];
#pragma unroll
      for (int m = 0; m < 4; m++) {
        int bl = bq + m * 8;
        size_t off = (size_t)(b0 + bl) * M_A + i0 + il;
        tile[il * 33 + bl] = th - z[off] - lam[off];
      }
    }
    __syncthreads();
    {
      int bl = tid & 31, iq = tid >> 5;
#pragma unroll
      for (int m = 0; m < 4; m++) {
        int il = iq + m * 8;
        VT[(size_t)(i0 + il) * BB + b0 + bl] = f2bf(tile[il * 33 + bl]);
      }
    }
  } else {
    // ---- tf: FT[j][b] (bf16), j = ld*16 + nt*2 + p, from F[b][p*8+nt][ld] ----
    int bx3 = bx - 8192;               // 0..511
    int j0 = (bx3 & 15) * 256, b0 = (bx3 >> 4) * 16;
    int ld0 = j0 >> 4;
    int cc = tid >> 4, dd = tid & 15;
    int jl = dd * 16 + ((cc & 7) << 1) + (cc >> 3);
    for (int m = 0; m < 16; m++) {
      tile[jl * 17 + m] = F[(size_t)(b0 + m) * 4096 + cc * 256 + ld0 + dd];
    }
    __syncthreads();
    int bl = tid & 15, jq = tid >> 4;
    for (int jj = 0; jj < 16; jj++) {
      int jlo = jq * 16 + jj;
      FT[(size_t)(j0 + jlo) * BB + b0 + bl] = f2bf(tile[jlo * 17 + bl]);
    }
  }
}

// ---------------- K1: lane owns 8 batches; wave owns a column; 16B gathers ----------------
__global__ __launch_bounds__(256) void k1_spmm(
    const u16* __restrict__ VT, const u16* __restrict__ FT,
    const int* __restrict__ colcnt, const int* __restrict__ csc_c,
    const float* __restrict__ lambda_W, const float* __restrict__ Lambda_A,
    const float* __restrict__ miu_p, const float* __restrict__ alpha_p,
    u16* __restrict__ UT) {
  __shared__ int idx[4 * COLCAP];
  __shared__ float lwS[512];
  __shared__ int cnts[4];
  __shared__ float lamA[4];
  int j0 = blockIdx.x * 4;
  int t = threadIdx.x;
  for (int s = t; s < 4 * COLCAP; s += 256) idx[s] = csc_c[j0 * COLCAP + s];
  for (int s = t; s < 512; s += 256) lwS[s] = lambda_W[s];
  if (t < 4) {
    cnts[t] = min(colcnt[j0 + t], COLCAP);
    lamA[t] = Lambda_A[j0 + t];
  }
  __syncthreads();
  int w = t >> 6, l = t & 63;
  int j = j0 + w;
  int boff = 8 * l;
  int cnt = cnts[w];
  const int* ic = &idx[w * COLCAP];
  float av[8] = {0, 0, 0, 0, 0, 0, 0, 0};
  int k = 0;
  for (; k + 1 < cnt; k += 2) {
    uint4 va = *(const uint4*)&VT[(size_t)ic[k] * BB + boff];
    uint4 vb = *(const uint4*)&VT[(size_t)ic[k + 1] * BB + boff];
    add8(va, av);
    add8(vb, av);
  }
  if (k < cnt) {
    uint4 va = *(const uint4*)&VT[(size_t)ic[k] * BB + boff];
    add8(va, av);
  }
  float miu = miu_p[0], alpha = alpha_p[0];
  float la = lamA[w];
  uint4 fr = *(const uint4*)&FT[(size_t)j * BB + boff];
  float res[8] = {bflo(fr.x), bfhi(fr.x), bflo(fr.y), bfhi(fr.y),
                  bflo(fr.z), bfhi(fr.z), bflo(fr.w), bfhi(fr.w)};
  u32 pk[4];
#pragma unroll
  for (int e = 0; e < 4; e++) {
    float lw0 = lwS[boff + 2 * e], lw1 = lwS[boff + 2 * e + 1];
    float q0 = miu * av[2 * e] + 2.0f * lw0 - 2.0f * SQ2 * res[2 * e] - alpha;
    float q1 = miu * av[2 * e + 1] + 2.0f * lw1 - 2.0f * SQ2 * res[2 * e + 1] - alpha;
    float w0 = 1.0f / (miu * la + 4.0f * lw0 - 2.0f * alpha);
    float w1 = 1.0f / (miu * la + 4.0f * lw1 - 2.0f * alpha);
    float u0 = fminf(fmaxf(q0 * w0, 0.0f), 1.0f);
    float u1 = fminf(fmaxf(q1 * w1, 0.0f), 1.0f);
    pk[e] = (u32)f2bf(u0) | ((u32)f2bf(u1) << 16);
  }
  *(uint4*)&UT[(size_t)j * BB + boff] = make_uint4(pk[0], pk[1], pk[2], pk[3]);
}

// ---------------- fused3: tu (out_u) + k2 (z/lam) + k3 (MMSE+F_new) ----------------
__global__ __launch_bounds__(256) void fused3(
    const u16* __restrict__ UT, const float* __restrict__ z_old,
    const float* __restrict__ lam_old, const float* __restrict__ theta,
    const float* __restrict__ relax_p, const float* __restrict__ acc_p,
    const int* __restrict__ rowcnt, const int* __restrict__ csr_c,
    float* __restrict__ out_u, float* __restrict__ out_z, float* __restrict__ out_lam,
    const float* __restrict__ real_Xp, const float* __restrict__ imag_Xp,
    const float* __restrict__ sigma2_I, const float* __restrict__ YYp,
    const float* __restrict__ Y, const float* __restrict__ lambda_W,
    const float* __restrict__ factor_p, const float* __restrict__ acc_new_in,
    float* __restrict__ out_lw, float* __restrict__ out_F, float* __restrict__ out_accnew) {
  __shared__ float smem[9696];  // 37.9 KB, re-cast per role
  int bidx = blockIdx.x;
  int tid = threadIdx.x;

  if (bidx < 2048) {
    // ---- tu: out_u[b][j] = f32(UT[j][b]) ----
    float* tile = smem;  // 32*33
    int j0 = (bidx & 127) * 32, b0 = (bidx >> 7) * 32;
    {
      int bl = tid & 31, jq = tid >> 5;
#pragma unroll
      for (int m = 0; m < 4; m++) {
        int jl = jq + m * 8;
        tile[jl * 33 + bl] = bflo((u32)UT[(size_t)(j0 + jl) * BB + b0 + bl]);
      }
    }
    __syncthreads();
    {
      int jl = tid & 31, bq = tid >> 5;
#pragma unroll
      for (int m = 0; m < 4; m++) {
        int bl = bq + m * 8;
        out_u[(size_t)(b0 + bl) * LDPC_N + j0 + jl] = tile[jl * 33 + bl];
      }
    }
  } else if (bidx < 2816) {
    // ---- k2: z/lambda1 update; lane owns 8 batches, wave owns 4 rows ----
    int* idx = (int*)smem;                 // [16][64]
    int* cnts = idx + 1024;                // 16
    float* ths = (float*)(idx + 1040);     // 16
    float* ssum = (float*)(idx + 1056);    // [16][520]
    int i0 = (bidx - 2048) * 16;
    for (int s = tid; s < 1024; s += 256) idx[s] = csr_c[i0 * ROWCAP + s];
    if (tid < 16) {
      cnts[tid] = min(rowcnt[i0 + tid], ROWCAP);
      ths[tid] = theta[i0 + tid];
    }
    __syncthreads();
    int w = tid >> 6, l = tid & 63, boff = 8 * l;
    for (int rr = 0; rr < 4; rr++) {
      int r = w * 4 + rr;
      int cnt = cnts[r];
      const int* ir = &idx[r * ROWCAP];
      float s[8] = {0, 0, 0, 0, 0, 0, 0, 0};
      int k = 0;
      for (; k + 1 < cnt; k += 2) {
        uint4 va = *(const uint4*)&UT[(size_t)ir[k] * BB + boff];
        uint4 vb = *(const uint4*)&UT[(size_t)ir[k + 1] * BB + boff];
        add8(va, s);
        add8(vb, s);
      }
      if (k < cnt) {
        uint4 va = *(const uint4*)&UT[(size_t)ir[k] * BB + boff];
        add8(va, s);
      }
      *(float4*)&ssum[r * 520 + boff] = make_float4(s[0], s[1], s[2], s[3]);
      *(float4*)&ssum[r * 520 + boff + 4] = make_float4(s[4], s[5], s[6], s[7]);
    }
    __syncthreads();
    float relax = relax_p[0], acc = acc_p[0];
    int iw = tid & 15, bq = tid >> 4;
    float th = ths[iw];
    if (relax == 1.0f && acc == 0.0f) {
      // fast path: z_old never affects outputs -> skip 25 MB of reads
      for (int p = 0; p < 32; p++) {
        int b = p * 16 + bq;
        size_t off = (size_t)b * M_A + i0 + iw;
        float lo = lam_old[off];
        float ztemp = th - ssum[iw * 520 + b] - lo;
        float zn = fmaxf(ztemp, 0.0f);
        out_z[off] = zn;
        out_lam[off] = zn - ztemp;
      }
    } else {
      for (int p = 0; p < 32; p++) {
        int b = p * 16 + bq;
        size_t off = (size_t)b * M_A + i0 + iw;
        float zo = z_old[off];
        float lo = lam_old[off];
        float s = ssum[iw * 520 + b];
        float ztemp = th - relax * s - (1.0f - relax) * (th - zo) - lo;
        float zn = fmaxf(ztemp, 0.0f);
        float ln = zn - ztemp;
        out_z[off] = zn + acc * (zn - zo);
        out_lam[off] = ln + acc * (ln - lo);
      }
    }
  } else {
    // ---- k3: per-batch MMSE solve + F_new ----
    float* XX = smem;              // [16][548] (pad 548: 16B-aligned rows)
    float* Rs = XX + 8768;         // [16][17]
    float* invd = Rs + 272;        // 16
    float* Tm = invd + 16;         // [16][8]
    float* Wcs = Tm + 128;         // 256
    float* Gs = Wcs + 256;         // 256
#define XXA(r, c) XX[(r) * 548 + (c)]
#define RLp(i, j) Rs[(i) * 17 + (j)]
    int b = bidx - 2816;

    // XX from UT (bit-identical to out_u = bflo(UT))
    for (int m = tid; m < 1024; m += 256) {
      int ld = m >> 2;
      int nt = (2 * m) & 7;
      int j4 = 4 * m;
      float q0 = bflo((u32)UT[(size_t)(j4 + 0) * BB + b]);
      float q1 = bflo((u32)UT[(size_t)(j4 + 1) * BB + b]);
      float q2 = bflo((u32)UT[(size_t)(j4 + 2) * BB + b]);
      float q3 = bflo((u32)UT[(size_t)(j4 + 3) * BB + b]);
      float vr0 = (1.0f - 2.0f * q0) * INVSQ2, vi0 = (1.0f - 2.0f * q1) * INVSQ2;
      float vr1 = (1.0f - 2.0f * q2) * INVSQ2, vi1 = (1.0f - 2.0f * q3) * INVSQ2;
      XXA(nt, ld) = vr0;          XXA(nt, 272 + ld) = vi0;
      XXA(8 + nt, ld) = -vi0;     XXA(8 + nt, 272 + ld) = vr0;
      XXA(nt + 1, ld) = vr1;      XXA(nt + 1, 272 + ld) = vi1;
      XXA(9 + nt, ld) = -vi1;     XXA(9 + nt, 272 + ld) = vr1;
    }
    if (tid < 128) {
      int r = tid >> 4, pc = tid & 15;
      float vr = real_Xp[(size_t)b * 128 + tid];
      float vi = imag_Xp[(size_t)b * 128 + tid];
      XXA(r, 256 + pc) = vr;       XXA(r, 528 + pc) = vi;
      XXA(8 + r, 256 + pc) = -vi;  XXA(8 + r, 528 + pc) = vr;
    }
    __syncthreads();

    // dots (float4): 136 R-triangle (LDS) + 128 T entries (YYp direct, L2-resident)
    const float4* XX4 = (const float4*)XX;  // row stride 137 float4
    for (int p = tid; p < 264; p += 256) {
      if (p < 136) {
        int i = 0;
        while ((i + 1) * (i + 2) / 2 <= p) i++;
        int jj = p - i * (i + 1) / 2;
        float s = 0.0f;
        for (int k4 = 0; k4 < 136; k4++) {
          float4 a = XX4[i * 137 + k4];
          float4 c = XX4[jj * 137 + k4];
          s += a.x * c.x + a.y * c.y + a.z * c.z + a.w * c.w;
        }
        RLp(i, jj) = s + sigma2_I[(size_t)b * 256 + i * 16 + jj];
      } else {
        int q = p - 136;
        int i = q >> 3, m = q & 7;
        const float4* yb4 = (const float4*)(YYp + (size_t)b * 4352 + m * 544);
        float s = 0.0f;
        for (int k4 = 0; k4 < 136; k4++) {
          float4 a = XX4[i * 137 + k4];
          float4 c = yb4[k4];
          s += a.x * c.x + a.y * c.y + a.z * c.z + a.w * c.w;
        }
        Tm[i * 8 + m] = s;
      }
    }
    __syncthreads();

    // Cholesky (full-block barriers — round-4 lesson: no barrier-free LDS ordering)
    for (int k = 0; k < 16; k++) {
      if (tid == 0) {
        float d = sqrtf(fmaxf(RLp(k, k), 1e-30f));
        RLp(k, k) = d;
        invd[k] = 1.0f / d;
      }
      __syncthreads();
      if (tid > k && tid < 16) RLp(tid, k) *= invd[k];
      __syncthreads();
      {
        int i = tid >> 4, jj = tid & 15;
        if (i > k && jj > k && jj <= i) RLp(i, jj) -= RLp(i, k) * RLp(jj, k);
      }
      __syncthreads();
    }

    // triangular solves: 8 lanes, register-resident (inputs finalized pre-barrier)
    if (tid < 8) {
      int m = tid;
      float yv[16], wv[16];
#pragma unroll
      for (int r = 0; r < 16; r++) {
        float s = Tm[r * 8 + m];
        for (int c = 0; c < r; c++) s -= RLp(r, c) * yv[c];
        yv[r] = s * invd[r];
      }
#pragma unroll
      for (int r = 15; r >= 0; r--) {
        float s = yv[r];
        for (int c = r + 1; c < 16; c++) s -= RLp(c, r) * wv[c];
        wv[r] = s * invd[r];
      }
#pragma unroll
      for (int r = 0; r < 16; r++) Tm[r * 8 + m] = wv[r];
    }
    __syncthreads();

    // Wc = WT = [[rW, iW],[-iW, rW]]
    {
      int i = tid >> 4, jj = tid & 15;
      int ii = i & 7, jc = jj & 7;
      float val;
      if (i < 8) val = (jj < 8) ? Tm[ii * 8 + jc] : Tm[(8 + ii) * 8 + jc];
      else       val = (jj < 8) ? -Tm[(8 + ii) * 8 + jc] : Tm[ii * 8 + jc];
      Wcs[tid] = val;
    }
    __syncthreads();
    {
      int i = tid >> 4, jj = tid & 15;
      float s = 0.0f;
#pragma unroll
      for (int k = 0; k < 16; k++) s += Wcs[i * 16 + k] * Wcs[jj * 16 + k];
      Gs[tid] = s;
    }
    __syncthreads();

    // F_new epilogue: thread = ld column
    float lw_new = factor_p[0] * lambda_W[b];
    {
      int ld = tid;
      float Xv[16], Yv[16];
#pragma unroll
      for (int c = 0; c < 8; c++) {
        Xv[c] = XXA(c, ld);
        Xv[8 + c] = XXA(c, 272 + ld);
      }
      const float* Yb = Y + (size_t)b * 16 * LDIM;
#pragma unroll
      for (int c = 0; c < 16; c++) Yv[c] = Yb[c * LDIM + ld];
      float* Fb = out_F + (size_t)b * 16 * LDIM;
      for (int r = 0; r < 16; r++) {
        float s = lw_new * Xv[r];
#pragma unroll
        for (int c = 0; c < 16; c++) s += Wcs[r * 16 + c] * Yv[c] - Gs[r * 16 + c] * Xv[c];
        Fb[r * LDIM + ld] = s;
      }
    }
    if (tid == 0) {
      out_lw[b] = lw_new;
      out_accnew[b] = acc_new_in[b];
    }
#undef XXA
#undef RLp
  }
}

extern "C" void kernel_launch(void* const* d_in, const int* in_sizes, int n_in,
                              void* d_out, int out_size, void* d_ws, size_t ws_size,
                              hipStream_t stream) {
  const float* sigma2_I  = (const float*)d_in[0];
  const float* Y         = (const float*)d_in[1];
  const float* YYp       = (const float*)d_in[2];
  const float* real_Xp   = (const float*)d_in[3];
  const float* imag_Xp   = (const float*)d_in[4];
  const float* lambda_W  = (const float*)d_in[5];
  const float* F         = (const float*)d_in[6];
  const float* z         = (const float*)d_in[8];
  const float* lam       = (const float*)d_in[9];
  const float* acc_new_i = (const float*)d_in[10];
  const float* A         = (const float*)d_in[11];
  const float* theta     = (const float*)d_in[12];
  const float* Lambda_A  = (const float*)d_in[13];
  const float* miu       = (const float*)d_in[14];
  const float* alpha     = (const float*)d_in[15];
  const float* factor    = (const float*)d_in[16];
  const float* relax     = (const float*)d_in[17];
  const float* acc       = (const float*)d_in[18];

  float* out = (float*)d_out;
  float* out_lw     = out;
  float* out_F      = out_lw + BB;
  float* out_u      = out_F + (size_t)BB * 2 * NT * LDIM;
  float* out_z      = out_u + (size_t)BB * LDPC_N;
  float* out_lam    = out_z + (size_t)BB * M_A;
  float* out_accnew = out_lam + (size_t)BB * M_A;

  // VT/FT alias not-yet-final out regions (k1 reads them; fused3's k2 overwrites after).
  u16* VT = (u16*)out_z;
  u16* FT = (u16*)out_lam;

  int* ws = (int*)d_ws;
  int* colcnt = ws;                       // 4096
  int* rowcnt = colcnt + LDPC_N;          // 12288
  int* csc_c  = rowcnt + M_A;             // COLCAP*4096
  int* csr_c  = csc_c + COLCAP * LDPC_N;  // ROWCAP*12288
  u16* UT     = (u16*)(csr_c + ROWCAP * M_A);  // 4096*512 bf16 (4.2 MB), in ws
                                               // (k3 writes out_F while tu/k2/k3 read UT)

  hipMemsetAsync(colcnt, 0, (LDPC_N + M_A) * sizeof(int), stream);
  prep<<<8704, 256, 0, stream>>>(A, colcnt, rowcnt, csc_c, csr_c,
                                 z, lam, theta, F, VT, FT);
  k1_spmm<<<LDPC_N / 4, 256, 0, stream>>>(VT, FT, colcnt, csc_c, lambda_W,
                                          Lambda_A, miu, alpha, UT);
  fused3<<<3328, 256, 0, stream>>>(UT, z, lam, theta, relax, acc, rowcnt, csr_c,
                                   out_u, out_z, out_lam,
                                   real_Xp, imag_Xp, sigma2_I, YYp, Y, lambda_W,
                                   factor, acc_new_i, out_lw, out_F, out_accnew);
}

// Round 10
// 469.606 us; speedup vs baseline: 1.6916x; 1.0404x over previous
//
#include <hip/hip_runtime.h>
#include <math.h>

#define BB 512
#define NT 8
#define NR 8
#define LDIM 256
#define LP 16
#define LDPC_N 4096
#define M_A 12288
#define COLCAP 128
#define ROWCAP 64
#define SQ2 1.41421356237309515f
#define INVSQ2 0.70710678118654752f

typedef unsigned short u16;
typedef unsigned int u32;

__device__ __forceinline__ float bflo(u32 u) { return __uint_as_float(u << 16); }
__device__ __forceinline__ float bfhi(u32 u) { return __uint_as_float(u & 0xffff0000u); }
__device__ __forceinline__ u16 f2bf(float f) {
  u32 b = __float_as_uint(f);
  return (u16)((b + 0x7fffu + ((b >> 16) & 1u)) >> 16);
}
__device__ __forceinline__ void add8(const uint4& v, float* a) {
  a[0] += bflo(v.x); a[1] += bfhi(v.x);
  a[2] += bflo(v.y); a[3] += bfhi(v.y);
  a[4] += bflo(v.z); a[5] += bfhi(v.z);
  a[6] += bflo(v.w); a[7] += bfhi(v.w);
}

// ---------------- prep: build sparse lists || VT transpose || FT transpose ----------------
__global__ __launch_bounds__(256) void prep(
    const float* __restrict__ A, int* __restrict__ colcnt, int* __restrict__ rowcnt,
    int* __restrict__ csc_c, int* __restrict__ csr_c,
    const float* __restrict__ z, const float* __restrict__ lam,
    const float* __restrict__ theta, const float* __restrict__ F,
    u16* __restrict__ VT, u16* __restrict__ FT) {
  __shared__ float tile[256 * 17];  // 17 KB; t1 uses 32*33 of it
  int bx = blockIdx.x;
  int tid = threadIdx.x;
  if (bx < 2048) {
    // ---- build: scan A, emit per-col/per-row index lists ----
    const long long total4 = (long long)M_A * LDPC_N / 4;
    const long long stride = 2048LL * 256LL;
    for (long long t = (long long)bx * 256 + tid; t < total4; t += stride) {
      float4 a = ((const float4*)A)[t];
      long long base = t * 4;
      float av[4] = {a.x, a.y, a.z, a.w};
#pragma unroll
      for (int l = 0; l < 4; l++) {
        if (av[l] != 0.0f) {
          long long lin = base + l;
          int i = (int)(lin >> 12);
          int j = (int)(lin & 4095);
          int sc = atomicAdd(&colcnt[j], 1);
          if (sc < COLCAP) csc_c[j * COLCAP + sc] = i;
          int sr = atomicAdd(&rowcnt[i], 1);
          if (sr < ROWCAP) csr_c[i * ROWCAP + sr] = j;
        }
      }
    }
  } else if (bx < 8192) {
    // ---- t1: VT[i][b] = theta[i]-z[b][i]-lam[b][i] (bf16) ----
    int bx2 = bx - 2048;
    int i0 = (bx2 % 384) * 32, b0 = (bx2 / 384) * 32;
    {
      int il = tid & 31, bq = tid >> 5;
      float th = theta[i0 + il];
#pragma unroll
      for (int m = 0; m < 4; m++) {
        int bl = bq + m * 8;
        size_t off = (size_t)(b0 + bl) * M_A + i0 + il;
        tile[il * 33 + bl] = th - z[off] - lam[off];
      }
    }
    __syncthreads();
    {
      int bl = tid & 31, iq = tid >> 5;
#pragma unroll
      for (int m = 0; m < 4; m++) {
        int il = iq + m * 8;
        VT[(size_t)(i0 + il) * BB + b0 + bl] = f2bf(tile[il * 33 + bl]);
      }
    }
  } else {
    // ---- tf: FT[j][b] (bf16), j = ld*16 + nt*2 + p, from F[b][p*8+nt][ld] ----
    int bx3 = bx - 8192;               // 0..511
    int j0 = (bx3 & 15) * 256, b0 = (bx3 >> 4) * 16;
    int ld0 = j0 >> 4;
    int cc = tid >> 4, dd = tid & 15;
    int jl = dd * 16 + ((cc & 7) << 1) + (cc >> 3);
    for (int m = 0; m < 16; m++) {
      tile[jl * 17 + m] = F[(size_t)(b0 + m) * 4096 + cc * 256 + ld0 + dd];
    }
    __syncthreads();
    int bl = tid & 15, jq = tid >> 4;
    for (int jj = 0; jj < 16; jj++) {
      int jlo = jq * 16 + jj;
      FT[(size_t)(j0 + jlo) * BB + b0 + bl] = f2bf(tile[jlo * 17 + bl]);
    }
  }
}

// ---------------- K1: lane owns 8 batches; wave owns a column; 16B gathers ----------------
__global__ __launch_bounds__(256) void k1_spmm(
    const u16* __restrict__ VT, const u16* __restrict__ FT,
    const int* __restrict__ colcnt, const int* __restrict__ csc_c,
    const float* __restrict__ lambda_W, const float* __restrict__ Lambda_A,
    const float* __restrict__ miu_p, const float* __restrict__ alpha_p,
    u16* __restrict__ UT) {
  __shared__ int idx[4 * COLCAP];
  __shared__ float lwS[512];
  __shared__ int cnts[4];
  __shared__ float lamA[4];
  int j0 = blockIdx.x * 4;
  int t = threadIdx.x;
  for (int s = t; s < 4 * COLCAP; s += 256) idx[s] = csc_c[j0 * COLCAP + s];
  for (int s = t; s < 512; s += 256) lwS[s] = lambda_W[s];
  if (t < 4) {
    cnts[t] = min(colcnt[j0 + t], COLCAP);
    lamA[t] = Lambda_A[j0 + t];
  }
  __syncthreads();
  int w = t >> 6, l = t & 63;
  int j = j0 + w;
  int boff = 8 * l;
  int cnt = cnts[w];
  const int* ic = &idx[w * COLCAP];
  float av[8] = {0, 0, 0, 0, 0, 0, 0, 0};
  int k = 0;
  for (; k + 1 < cnt; k += 2) {
    uint4 va = *(const uint4*)&VT[(size_t)ic[k] * BB + boff];
    uint4 vb = *(const uint4*)&VT[(size_t)ic[k + 1] * BB + boff];
    add8(va, av);
    add8(vb, av);
  }
  if (k < cnt) {
    uint4 va = *(const uint4*)&VT[(size_t)ic[k] * BB + boff];
    add8(va, av);
  }
  float miu = miu_p[0], alpha = alpha_p[0];
  float la = lamA[w];
  uint4 fr = *(const uint4*)&FT[(size_t)j * BB + boff];
  float res[8] = {bflo(fr.x), bfhi(fr.x), bflo(fr.y), bfhi(fr.y),
                  bflo(fr.z), bfhi(fr.z), bflo(fr.w), bfhi(fr.w)};
  u32 pk[4];
#pragma unroll
  for (int e = 0; e < 4; e++) {
    float lw0 = lwS[boff + 2 * e], lw1 = lwS[boff + 2 * e + 1];
    float q0 = miu * av[2 * e] + 2.0f * lw0 - 2.0f * SQ2 * res[2 * e] - alpha;
    float q1 = miu * av[2 * e + 1] + 2.0f * lw1 - 2.0f * SQ2 * res[2 * e + 1] - alpha;
    float w0 = 1.0f / (miu * la + 4.0f * lw0 - 2.0f * alpha);
    float w1 = 1.0f / (miu * la + 4.0f * lw1 - 2.0f * alpha);
    float u0 = fminf(fmaxf(q0 * w0, 0.0f), 1.0f);
    float u1 = fminf(fmaxf(q1 * w1, 0.0f), 1.0f);
    pk[e] = (u32)f2bf(u0) | ((u32)f2bf(u1) << 16);
  }
  *(uint4*)&UT[(size_t)j * BB + boff] = make_uint4(pk[0], pk[1], pk[2], pk[3]);
}

// ---------------- fused2: k3 (MMSE+F_new+out_u) FIRST, then k2 (z/lam) ----------------
__global__ __launch_bounds__(256) void fused2(
    const u16* __restrict__ UT, const float* __restrict__ z_old,
    const float* __restrict__ lam_old, const float* __restrict__ theta,
    const float* __restrict__ relax_p, const float* __restrict__ acc_p,
    const int* __restrict__ rowcnt, const int* __restrict__ csr_c,
    float* __restrict__ out_u, float* __restrict__ out_z, float* __restrict__ out_lam,
    const float* __restrict__ real_Xp, const float* __restrict__ imag_Xp,
    const float* __restrict__ sigma2_I, const float* __restrict__ YYp,
    const float* __restrict__ Y, const float* __restrict__ lambda_W,
    const float* __restrict__ factor_p, const float* __restrict__ acc_new_in,
    float* __restrict__ out_lw, float* __restrict__ out_F, float* __restrict__ out_accnew) {
  __shared__ float smem[9696];  // 37.9 KB, re-cast per role
  int bidx = blockIdx.x;
  int tid = threadIdx.x;

  if (bidx < 512) {
    // ---- k3: per-batch MMSE solve + F_new + out_u (launched FIRST: longest critical path) ----
    float* XX = smem;              // [16][548] (pad 548: 16B-aligned rows)
    float* Rs = XX + 8768;         // [16][17]
    float* invd = Rs + 272;        // 16
    float* Tm = invd + 16;         // [16][8]
    float* Wcs = Tm + 128;         // 256
    float* Gs = Wcs + 256;         // 256
#define XXA(r, c) XX[(r) * 548 + (c)]
#define RLp(i, j) Rs[(i) * 17 + (j)]
    int b = bidx;

    // XX from UT; also emit out_u[b][:] (bit-identical to former tu: bflo(UT))
    for (int m = tid; m < 1024; m += 256) {
      int ld = m >> 2;
      int nt = (2 * m) & 7;
      int j4 = 4 * m;
      float q0 = bflo((u32)UT[(size_t)(j4 + 0) * BB + b]);
      float q1 = bflo((u32)UT[(size_t)(j4 + 1) * BB + b]);
      float q2 = bflo((u32)UT[(size_t)(j4 + 2) * BB + b]);
      float q3 = bflo((u32)UT[(size_t)(j4 + 3) * BB + b]);
      *(float4*)&out_u[(size_t)b * LDPC_N + j4] = make_float4(q0, q1, q2, q3);
      float vr0 = (1.0f - 2.0f * q0) * INVSQ2, vi0 = (1.0f - 2.0f * q1) * INVSQ2;
      float vr1 = (1.0f - 2.0f * q2) * INVSQ2, vi1 = (1.0f - 2.0f * q3) * INVSQ2;
      XXA(nt, ld) = vr0;          XXA(nt, 272 + ld) = vi0;
      XXA(8 + nt, ld) = -vi0;     XXA(8 + nt, 272 + ld) = vr0;
      XXA(nt + 1, ld) = vr1;      XXA(nt + 1, 272 + ld) = vi1;
      XXA(9 + nt, ld) = -vi1;     XXA(9 + nt, 272 + ld) = vr1;
    }
    if (tid < 128) {
      int r = tid >> 4, pc = tid & 15;
      float vr = real_Xp[(size_t)b * 128 + tid];
      float vi = imag_Xp[(size_t)b * 128 + tid];
      XXA(r, 256 + pc) = vr;       XXA(r, 528 + pc) = vi;
      XXA(8 + r, 256 + pc) = -vi;  XXA(8 + r, 528 + pc) = vr;
    }
    __syncthreads();

    // dots (float4): 136 R-triangle (LDS) + 128 T entries (YYp direct, L2-resident)
    const float4* XX4 = (const float4*)XX;  // row stride 137 float4
    for (int p = tid; p < 264; p += 256) {
      if (p < 136) {
        int i = 0;
        while ((i + 1) * (i + 2) / 2 <= p) i++;
        int jj = p - i * (i + 1) / 2;
        float s = 0.0f;
        for (int k4 = 0; k4 < 136; k4++) {
          float4 a = XX4[i * 137 + k4];
          float4 c = XX4[jj * 137 + k4];
          s += a.x * c.x + a.y * c.y + a.z * c.z + a.w * c.w;
        }
        RLp(i, jj) = s + sigma2_I[(size_t)b * 256 + i * 16 + jj];
      } else {
        int q = p - 136;
        int i = q >> 3, m = q & 7;
        const float4* yb4 = (const float4*)(YYp + (size_t)b * 4352 + m * 544);
        float s = 0.0f;
        for (int k4 = 0; k4 < 136; k4++) {
          float4 a = XX4[i * 137 + k4];
          float4 c = yb4[k4];
          s += a.x * c.x + a.y * c.y + a.z * c.z + a.w * c.w;
        }
        Tm[i * 8 + m] = s;
      }
    }
    __syncthreads();

    // Cholesky (full-block barriers — round-4 lesson: no barrier-free LDS ordering)
    for (int k = 0; k < 16; k++) {
      if (tid == 0) {
        float d = sqrtf(fmaxf(RLp(k, k), 1e-30f));
        RLp(k, k) = d;
        invd[k] = 1.0f / d;
      }
      __syncthreads();
      if (tid > k && tid < 16) RLp(tid, k) *= invd[k];
      __syncthreads();
      {
        int i = tid >> 4, jj = tid & 15;
        if (i > k && jj > k && jj <= i) RLp(i, jj) -= RLp(i, k) * RLp(jj, k);
      }
      __syncthreads();
    }

    // triangular solves: 8 lanes, register-resident (inputs finalized pre-barrier)
    if (tid < 8) {
      int m = tid;
      float yv[16], wv[16];
#pragma unroll
      for (int r = 0; r < 16; r++) {
        float s = Tm[r * 8 + m];
        for (int c = 0; c < r; c++) s -= RLp(r, c) * yv[c];
        yv[r] = s * invd[r];
      }
#pragma unroll
      for (int r = 15; r >= 0; r--) {
        float s = yv[r];
        for (int c = r + 1; c < 16; c++) s -= RLp(c, r) * wv[c];
        wv[r] = s * invd[r];
      }
#pragma unroll
      for (int r = 0; r < 16; r++) Tm[r * 8 + m] = wv[r];
    }
    __syncthreads();

    // Wc = WT = [[rW, iW],[-iW, rW]]
    {
      int i = tid >> 4, jj = tid & 15;
      int ii = i & 7, jc = jj & 7;
      float val;
      if (i < 8) val = (jj < 8) ? Tm[ii * 8 + jc] : Tm[(8 + ii) * 8 + jc];
      else       val = (jj < 8) ? -Tm[(8 + ii) * 8 + jc] : Tm[ii * 8 + jc];
      Wcs[tid] = val;
    }
    __syncthreads();
    {
      int i = tid >> 4, jj = tid & 15;
      float s = 0.0f;
#pragma unroll
      for (int k = 0; k < 16; k++) s += Wcs[i * 16 + k] * Wcs[jj * 16 + k];
      Gs[tid] = s;
    }
    __syncthreads();

    // F_new epilogue: thread = ld column
    float lw_new = factor_p[0] * lambda_W[b];
    {
      int ld = tid;
      float Xv[16], Yv[16];
#pragma unroll
      for (int c = 0; c < 8; c++) {
        Xv[c] = XXA(c, ld);
        Xv[8 + c] = XXA(c, 272 + ld);
      }
      const float* Yb = Y + (size_t)b * 16 * LDIM;
#pragma unroll
      for (int c = 0; c < 16; c++) Yv[c] = Yb[c * LDIM + ld];
      float* Fb = out_F + (size_t)b * 16 * LDIM;
      for (int r = 0; r < 16; r++) {
        float s = lw_new * Xv[r];
#pragma unroll
        for (int c = 0; c < 16; c++) s += Wcs[r * 16 + c] * Yv[c] - Gs[r * 16 + c] * Xv[c];
        Fb[r * LDIM + ld] = s;
      }
    }
    if (tid == 0) {
      out_lw[b] = lw_new;
      out_accnew[b] = acc_new_in[b];
    }
#undef XXA
#undef RLp
  } else {
    // ---- k2: z/lambda1 update; lane owns 8 batches, wave owns 4 rows ----
    int* idx = (int*)smem;                 // [16][64]
    int* cnts = idx + 1024;                // 16
    float* ths = (float*)(idx + 1040);     // 16
    float* ssum = (float*)(idx + 1056);    // [16][520]
    int i0 = (bidx - 512) * 16;
    for (int s = tid; s < 1024; s += 256) idx[s] = csr_c[i0 * ROWCAP + s];
    if (tid < 16) {
      cnts[tid] = min(rowcnt[i0 + tid], ROWCAP);
      ths[tid] = theta[i0 + tid];
    }
    __syncthreads();
    int w = tid >> 6, l = tid & 63, boff = 8 * l;
    for (int rr = 0; rr < 4; rr++) {
      int r = w * 4 + rr;
      int cnt = cnts[r];
      const int* ir = &idx[r * ROWCAP];
      float s[8] = {0, 0, 0, 0, 0, 0, 0, 0};
      int k = 0;
      for (; k + 1 < cnt; k += 2) {
        uint4 va = *(const uint4*)&UT[(size_t)ir[k] * BB + boff];
        uint4 vb = *(const uint4*)&UT[(size_t)ir[k + 1] * BB + boff];
        add8(va, s);
        add8(vb, s);
      }
      if (k < cnt) {
        uint4 va = *(const uint4*)&UT[(size_t)ir[k] * BB + boff];
        add8(va, s);
      }
      *(float4*)&ssum[r * 520 + boff] = make_float4(s[0], s[1], s[2], s[3]);
      *(float4*)&ssum[r * 520 + boff + 4] = make_float4(s[4], s[5], s[6], s[7]);
    }
    __syncthreads();
    float relax = relax_p[0], acc = acc_p[0];
    int iw = tid & 15, bq = tid >> 4;
    float th = ths[iw];
    if (relax == 1.0f && acc == 0.0f) {
      // fast path: z_old never affects outputs -> skip 25 MB of reads
      for (int p = 0; p < 32; p++) {
        int b = p * 16 + bq;
        size_t off = (size_t)b * M_A + i0 + iw;
        float lo = lam_old[off];
        float ztemp = th - ssum[iw * 520 + b] - lo;
        float zn = fmaxf(ztemp, 0.0f);
        out_z[off] = zn;
        out_lam[off] = zn - ztemp;
      }
    } else {
      for (int p = 0; p < 32; p++) {
        int b = p * 16 + bq;
        size_t off = (size_t)b * M_A + i0 + iw;
        float zo = z_old[off];
        float lo = lam_old[off];
        float s = ssum[iw * 520 + b];
        float ztemp = th - relax * s - (1.0f - relax) * (th - zo) - lo;
        float zn = fmaxf(ztemp, 0.0f);
        float ln = zn - ztemp;
        out_z[off] = zn + acc * (zn - zo);
        out_lam[off] = ln + acc * (ln - lo);
      }
    }
  }
}

extern "C" void kernel_launch(void* const* d_in, const int* in_sizes, int n_in,
                              void* d_out, int out_size, void* d_ws, size_t ws_size,
                              hipStream_t stream) {
  const float* sigma2_I  = (const float*)d_in[0];
  const float* Y         = (const float*)d_in[1];
  const float* YYp       = (const float*)d_in[2];
  const float* real_Xp   = (const float*)d_in[3];
  const float* imag_Xp   = (const float*)d_in[4];
  const float* lambda_W  = (const float*)d_in[5];
  const float* F         = (const float*)d_in[6];
  const float* z         = (const float*)d_in[8];
  const float* lam       = (const float*)d_in[9];
  const float* acc_new_i = (const float*)d_in[10];
  const float* A         = (const float*)d_in[11];
  const float* theta     = (const float*)d_in[12];
  const float* Lambda_A  = (const float*)d_in[13];
  const float* miu       = (const float*)d_in[14];
  const float* alpha     = (const float*)d_in[15];
  const float* factor    = (const float*)d_in[16];
  const float* relax     = (const float*)d_in[17];
  const float* acc       = (const float*)d_in[18];

  float* out = (float*)d_out;
  float* out_lw     = out;
  float* out_F      = out_lw + BB;
  float* out_u      = out_F + (size_t)BB * 2 * NT * LDIM;
  float* out_z      = out_u + (size_t)BB * LDPC_N;
  float* out_lam    = out_z + (size_t)BB * M_A;
  float* out_accnew = out_lam + (size_t)BB * M_A;

  // VT/FT alias not-yet-final out regions (k1 reads them; fused2's k2 overwrites after).
  u16* VT = (u16*)out_z;
  u16* FT = (u16*)out_lam;

  int* ws = (int*)d_ws;
  int* colcnt = ws;                       // 4096
  int* rowcnt = colcnt + LDPC_N;          // 12288
  int* csc_c  = rowcnt + M_A;             // COLCAP*4096
  int* csr_c  = csc_c + COLCAP * LDPC_N;  // ROWCAP*12288
  u16* UT     = (u16*)(csr_c + ROWCAP * M_A);  // 4096*512 bf16 (4.2 MB), in ws

  hipMemsetAsync(colcnt, 0, (LDPC_N + M_A) * sizeof(int), stream);
  prep<<<8704, 256, 0, stream>>>(A, colcnt, rowcnt, csc_c, csr_c,
                                 z, lam, theta, F, VT, FT);
  k1_spmm<<<LDPC_N / 4, 256, 0, stream>>>(VT, FT, colcnt, csc_c, lambda_W,
                                          Lambda_A, miu, alpha, UT);
  fused2<<<1280, 256, 0, stream>>>(UT, z, lam, theta, relax, acc, rowcnt, csr_c,
                                   out_u, out_z, out_lam,
                                   real_Xp, imag_Xp, sigma2_I, YYp, Y, lambda_W,
                                   factor, acc_new_i, out_lw, out_F, out_accnew);
}